// Round 6
// baseline (282.019 us; speedup 1.0000x reference)
//
#include <hip/hip_runtime.h>

typedef short bf16x8 __attribute__((ext_vector_type(8)));
typedef float f32x4 __attribute__((ext_vector_type(4)));

__device__ inline float bf2f(ushort u) {
    unsigned v = ((unsigned)u) << 16;
    return __builtin_bit_cast(float, v);
}
__device__ inline ushort f2bf(float f) {
    unsigned u = __builtin_bit_cast(unsigned, f);
    u += 0x7fffu + ((u >> 16) & 1u);
    return (ushort)(u >> 16);
}
__device__ inline void async_load16(const ushort* g, ushort* l) {
    __builtin_amdgcn_global_load_lds((const __attribute__((address_space(1))) void*)g,
                                     (__attribute__((address_space(3))) void*)l, 16, 0, 0);
}

// Single merged fp32->bf16 cast for all 5 tensors. 8 elems/thread, 2048/block.
// Ranges (blocks): hs 2048 | Wq 512 | Wk 512 | Wv 512 | Ws 128  => grid 3712
__global__ void cast_all(const float* __restrict__ hs, const float* __restrict__ Wq,
                         const float* __restrict__ Wk, const float* __restrict__ Wv,
                         const float* __restrict__ Ws,
                         ushort* __restrict__ dhs, ushort* __restrict__ dWq,
                         ushort* __restrict__ dWk, ushort* __restrict__ dWv,
                         ushort* __restrict__ dWs)
{
    int bid = blockIdx.x;
    const float* src; ushort* dst; int off;
    if (bid < 2048)      { src = hs; dst = dhs; off = bid; }
    else if (bid < 2560) { src = Wq; dst = dWq; off = bid - 2048; }
    else if (bid < 3072) { src = Wk; dst = dWk; off = bid - 2560; }
    else if (bid < 3584) { src = Wv; dst = dWv; off = bid - 3072; }
    else                 { src = Ws; dst = dWs; off = bid - 3584; }
    int i = (off * 256 + threadIdx.x) * 8;
    float4 a = *(const float4*)(src + i);
    float4 b = *(const float4*)(src + i + 4);
    union { ushort u[8]; float4 v; } o;
    o.u[0] = f2bf(a.x); o.u[1] = f2bf(a.y); o.u[2] = f2bf(a.z); o.u[3] = f2bf(a.w);
    o.u[4] = f2bf(b.x); o.u[5] = f2bf(b.y); o.u[6] = f2bf(b.z); o.u[7] = f2bf(b.w);
    *(float4*)(dst + i) = o.v;
}

// Fused QKVS projection. X:[4096,1024] bf16, W*:[N,1024] bf16 row-major, bias fp32.
// xb 0-7 -> Q (scaled 0.125*log2e), 8-15 -> K, 16-23 -> V (transposed to VtG[bh][d][s]),
// 24-25 -> S (sigmoid -> fp32 sb). LDS XOR chunk swizzle: chunk c of row r at slot c^(r&7).
__launch_bounds__(256, 4)
__global__ void fused_qkvs(const ushort* __restrict__ X,
                           const ushort* __restrict__ Wq, const ushort* __restrict__ Wk,
                           const ushort* __restrict__ Wv, const ushort* __restrict__ Ws,
                           const float* __restrict__ bq, const float* __restrict__ bk,
                           const float* __restrict__ bv, const float* __restrict__ bs,
                           ushort* __restrict__ Qb, ushort* __restrict__ Kb,
                           ushort* __restrict__ VtG, float* __restrict__ sb)
{
    __shared__ __align__(16) ushort Sm[128 * 136];   // epilogue scratch; aliases As/Bs
    ushort* As = Sm;                 // 128 rows x 64 cols (swizzled)
    ushort* Bs = Sm + 128 * 64;

    const int tid = threadIdx.x, w = tid >> 6, lane = tid & 63;
    const int l15 = lane & 15, quad = lane >> 4;
    const int lrow = lane >> 3;
    const int gchunk = ((lane & 7) ^ lrow) * 8;   // swizzled global chunk for staging

    const int wid = blockIdx.x;
    const int r8 = wid & 7, jj = wid >> 3;
    const int by = (jj & 3) * 8 + r8;    // 0..31
    const int xb = jj >> 2;              // 0..25
    const int m0 = by * 128;

    const ushort* W; const float* bias; int n0, mode;
    if (xb < 8)       { W = Wq; bias = bq; n0 = xb * 128;        mode = 1; }
    else if (xb < 16) { W = Wk; bias = bk; n0 = (xb - 8) * 128;  mode = 0; }
    else if (xb < 24) { W = Wv; bias = bv; n0 = (xb - 16) * 128; mode = 2; }
    else              { W = Ws; bias = bs; n0 = (xb - 24) * 128; mode = 3; }

    const int wm = (w >> 1) * 64, wn = (w & 1) * 64;

    f32x4 acc[4][4];
    for (int i = 0; i < 4; i++) for (int j = 0; j < 4; j++) acc[i][j] = (f32x4){0.f, 0.f, 0.f, 0.f};

    for (int k0 = 0; k0 < 1024; k0 += 64) {
        __syncthreads();
        for (int c = 0; c < 4; ++c) {
            int r = w * 32 + c * 8;
            async_load16(&X[(size_t)(m0 + r + lrow) * 1024 + k0 + gchunk], &As[r * 64]);
            async_load16(&W[(size_t)(n0 + r + lrow) * 1024 + k0 + gchunk], &Bs[r * 64]);
        }
        __syncthreads();
        for (int kk = 0; kk < 64; kk += 32) {
            const int csw = quad + (kk >> 3);
            bf16x8 a[4], b[4];
            for (int i = 0; i < 4; i++)
                a[i] = *(const bf16x8*)&As[(wm + i * 16 + l15) * 64 + ((csw ^ (l15 & 7)) * 8)];
            for (int j = 0; j < 4; j++)
                b[j] = *(const bf16x8*)&Bs[(wn + j * 16 + l15) * 64 + ((csw ^ (l15 & 7)) * 8)];
            for (int i = 0; i < 4; i++)
                for (int j = 0; j < 4; j++)
                    acc[i][j] = __builtin_amdgcn_mfma_f32_16x16x32_bf16(a[i], b[j], acc[i][j], 0, 0, 0);
        }
    }

    const float QSCALE = 0.125f * 1.44269504f;  // 1/sqrt(D) and ln->log2 folded into Q

    if (mode == 3) {
        for (int i = 0; i < 4; i++)
            for (int j = 0; j < 4; j++) {
                int gn = n0 + wn + j * 16 + l15;
                float bv_ = bias[gn];
                for (int r = 0; r < 4; r++) {
                    int gm = m0 + wm + i * 16 + quad * 4 + r;
                    float v = acc[i][j][r] + bv_;
                    float sg = 1.0f / (1.0f + exp2f(-v * 1.44269504f));
                    sb[(size_t)gm * 256 + gn] = sg * 0.1f + 0.95f;
                }
            }
        return;
    }

    __syncthreads();  // main loop done with As/Bs; Sm becomes epilogue scratch

    if (mode == 2) {
        for (int i = 0; i < 4; i++)
            for (int j = 0; j < 4; j++) {
                int gnl = wn + j * 16 + l15;
                float bv_ = bias[n0 + gnl];
                ushort4 pk;
                pk.x = f2bf(acc[i][j][0] + bv_);
                pk.y = f2bf(acc[i][j][1] + bv_);
                pk.z = f2bf(acc[i][j][2] + bv_);
                pk.w = f2bf(acc[i][j][3] + bv_);
                *(ushort4*)&Sm[gnl * 136 + wm + i * 16 + quad * 4] = pk;
            }
        __syncthreads();
        const int bb = m0 >> 11, sloc = m0 & 2047;
        for (int it = 0; it < 8; ++it) {
            int d = (tid >> 4) + it * 16;
            int s8 = (tid & 15) * 8;
            float4 v = *(float4*)&Sm[d * 136 + s8];
            int h = (n0 + d) >> 6, dd = d & 63;
            *(float4*)&VtG[(size_t)(bb * 16 + h) * 131072 + (size_t)dd * 2048 + sloc + s8] = v;
        }
    } else {
        for (int i = 0; i < 4; i++)
            for (int j = 0; j < 4; j++) {
                int gnl = wn + j * 16 + l15;
                float bv_ = bias[n0 + gnl];
                for (int r = 0; r < 4; r++) {
                    float v = acc[i][j][r] + bv_;
                    if (mode == 1) v *= QSCALE;
                    Sm[(wm + i * 16 + quad * 4 + r) * 136 + gnl] = f2bf(v);
                }
            }
        __syncthreads();
        ushort* dst = (mode == 1) ? Qb : Kb;
        for (int it = 0; it < 8; ++it) {
            int row = (tid >> 4) + it * 16, c = (tid & 15) * 8;
            *(float4*)&dst[(size_t)(m0 + row) * 1024 + n0 + c] = *(float4*)&Sm[row * 136 + c];
        }
    }
}

// Flash attention, no-max softmax (log2e folded into Q).
// Q:[4096,1024] bf16 (pre-scaled; groupwise s applied during Qs staging),
// K:[4096,1024] bf16, Vt:[32][64][2048] bf16, out fp32 [4096,1024].
// flat grid 512 (XCD-swizzled), block 256.
// NO in-loop barriers: K/V B-frags loaded global->register (L2-resident),
// Q A-frags hoisted to registers, Ps is wave-private (lgkmcnt ordering only).
__launch_bounds__(256, 3)
__global__ void attn_kernel(const ushort* __restrict__ Q, const ushort* __restrict__ K,
                            const ushort* __restrict__ Vt, const float* __restrict__ sb,
                            float* __restrict__ out)
{
    __shared__ __align__(16) ushort Qs[128 * 72];
    __shared__ __align__(16) ushort Ps[128 * 72];

    const int tid = threadIdx.x, w = tid >> 6, lane = tid & 63;
    const int l15 = lane & 15, quad = lane >> 4;

    // XCD swizzle: same bh (same K/V) -> same XCD
    const int wid = blockIdx.x;
    const int r8 = wid & 7, jj = wid >> 3;
    const int bh = (jj & 3) * 8 + r8;    // 0..31
    const int qx = jj >> 2;              // 0..15
    const int b = bh >> 4, h = bh & 15;
    const int q0 = qx * 128;
    const size_t rowbase = (size_t)b * 2048;
    const int cbase = h * 64;

    // stage Q tile (apply groupwise scale s; s index for col n is n>>2)
    for (int it = 0; it < 4; ++it) {
        int l = tid + it * 256;
        int r = l >> 3, c = (l & 7) * 8;
        union { float4 f; ushort u[8]; } uu, oo;
        uu.f = *(const float4*)&Q[(rowbase + q0 + r) * 1024 + cbase + c];
        const float* sp = &sb[(rowbase + q0 + r) * 256 + ((cbase + c) >> 2)];
        float s0 = sp[0], s1 = sp[1];
        for (int j = 0; j < 4; j++) oo.u[j] = f2bf(bf2f(uu.u[j]) * s0);
        for (int j = 4; j < 8; j++) oo.u[j] = f2bf(bf2f(uu.u[j]) * s1);
        *(float4*)&Qs[r * 72 + c] = oo.f;
    }
    __syncthreads();  // the only barrier

    // hoist loop-invariant Q A-frags to registers
    bf16x8 aq[2][2];  // [mt][kk2]
    for (int mt = 0; mt < 2; mt++)
        for (int kk2 = 0; kk2 < 2; kk2++)
            aq[mt][kk2] = *(const bf16x8*)&Qs[(w * 32 + mt * 16 + l15) * 72 + kk2 * 32 + quad * 8];

    const ushort* Kbase = K + rowbase * 1024 + cbase;         // K[key][d], stride 1024
    const ushort* Vbase = Vt + (size_t)bh * 131072;           // Vt[d][k], stride 2048

    float lsum[2][4];
    f32x4 o[2][4];
    for (int mt = 0; mt < 2; mt++) for (int r = 0; r < 4; r++) lsum[mt][r] = 0.f;
    for (int mt = 0; mt < 2; mt++) for (int nt = 0; nt < 4; nt++) o[mt][nt] = (f32x4){0.f, 0.f, 0.f, 0.f};

    for (int kt = 0; kt < 32; ++kt) {
        const int k0 = kt * 64;

        // K B-frags: lane l15 = key, quad*8 = d offset. V B-frags: lane l15 = d, quad*8 = k.
        bf16x8 kb[2][4], vb[2][4];
        for (int kk2 = 0; kk2 < 2; kk2++)
            for (int nt = 0; nt < 4; nt++) {
                kb[kk2][nt] = *(const bf16x8*)&Kbase[(size_t)(k0 + nt * 16 + l15) * 1024 + kk2 * 32 + quad * 8];
                vb[kk2][nt] = *(const bf16x8*)&Vbase[(size_t)(nt * 16 + l15) * 2048 + k0 + kk2 * 32 + quad * 8];
            }

        f32x4 sacc[2][4];
        for (int mt = 0; mt < 2; mt++)
            for (int nt = 0; nt < 4; nt++) sacc[mt][nt] = (f32x4){0.f, 0.f, 0.f, 0.f};
        for (int kk2 = 0; kk2 < 2; kk2++)
            for (int mt = 0; mt < 2; mt++)
                for (int nt = 0; nt < 4; nt++)
                    sacc[mt][nt] = __builtin_amdgcn_mfma_f32_16x16x32_bf16(aq[mt][kk2], kb[kk2][nt],
                                                                           sacc[mt][nt], 0, 0, 0);

        // no-max softmax: p = exp2(score_pre-scaled); accumulate row sums; stash P
        for (int mt = 0; mt < 2; mt++)
            for (int nt = 0; nt < 4; nt++)
                for (int r = 0; r < 4; r++) {
                    float p = exp2f(sacc[mt][nt][r]);
                    lsum[mt][r] += p;
                    Ps[(w * 32 + mt * 16 + quad * 4 + r) * 72 + nt * 16 + l15] = f2bf(p);
                }

        // O += P @ V   (Ps strip wave-private; compiler inserts lgkmcnt wait)
        for (int kk2 = 0; kk2 < 2; kk2++) {
            bf16x8 a[2];
            for (int mt = 0; mt < 2; mt++)
                a[mt] = *(const bf16x8*)&Ps[(w * 32 + mt * 16 + l15) * 72 + kk2 * 32 + quad * 8];
            for (int mt = 0; mt < 2; mt++)
                for (int nt = 0; nt < 4; nt++)
                    o[mt][nt] = __builtin_amdgcn_mfma_f32_16x16x32_bf16(a[mt], vb[kk2][nt],
                                                                        o[mt][nt], 0, 0, 0);
        }
    }

    for (int mt = 0; mt < 2; mt++)
        for (int r = 0; r < 4; r++) {
            float s = lsum[mt][r];
            for (int off = 1; off < 16; off <<= 1) s += __shfl_xor(s, off);
            lsum[mt][r] = s;
        }

    for (int mt = 0; mt < 2; mt++) {
        for (int r = 0; r < 4; r++) {
            float inv = 1.0f / lsum[mt][r];
            int q = q0 + w * 32 + mt * 16 + quad * 4 + r;
            size_t base = (rowbase + q) * 1024 + cbase;
            for (int nt = 0; nt < 4; nt++)
                out[base + nt * 16 + l15] = o[mt][nt][r] * inv;
        }
    }
}

extern "C" void kernel_launch(void* const* d_in, const int* in_sizes, int n_in,
                              void* d_out, int out_size, void* d_ws, size_t ws_size,
                              hipStream_t stream) {
    const float* hs = (const float*)d_in[0];
    const float* Wq = (const float*)d_in[1];
    const float* bq = (const float*)d_in[2];
    const float* Wk = (const float*)d_in[3];
    const float* bk = (const float*)d_in[4];
    const float* Wv = (const float*)d_in[5];
    const float* bv = (const float*)d_in[6];
    const float* Ws = (const float*)d_in[7];
    const float* bs = (const float*)d_in[8];
    float* outp = (float*)d_out;

    char* ws = (char*)d_ws;
    ushort* Qb    = (ushort*)(ws);                 //  8 MB
    ushort* Kb    = (ushort*)(ws + 8388608);       //  8 MB
    ushort* VtG   = (ushort*)(ws + 16777216);      //  8 MB (V transposed [bh][d][s])
    float*  sb    = (float* )(ws + 25165824);      //  4 MB
    ushort* hs_bf = (ushort*)(ws + 29360128);      //  8 MB
    ushort* Wq_bf = (ushort*)(ws + 37748736);      //  2 MB
    ushort* Wk_bf = (ushort*)(ws + 39845888);      //  2 MB
    ushort* Wv_bf = (ushort*)(ws + 41943040);      //  2 MB
    ushort* Ws_bf = (ushort*)(ws + 44040192);      // 0.5 MB -> total 44,564,480 B

    dim3 blk(256);
    cast_all<<<dim3(3712), blk, 0, stream>>>(hs, Wq, Wk, Wv, Ws,
                                             hs_bf, Wq_bf, Wk_bf, Wv_bf, Ws_bf);
    fused_qkvs<<<dim3(832), blk, 0, stream>>>(hs_bf, Wq_bf, Wk_bf, Wv_bf, Ws_bf,
                                              bq, bk, bv, bs, Qb, Kb, VtG, sb);
    attn_kernel<<<dim3(512), blk, 0, stream>>>(Qb, Kb, VtG, sb, outp);
}

// Round 7
// 253.066 us; speedup vs baseline: 1.1144x; 1.1144x over previous
//
#include <hip/hip_runtime.h>

typedef short bf16x8 __attribute__((ext_vector_type(8)));
typedef float f32x4 __attribute__((ext_vector_type(4)));

__device__ inline float bf2f(ushort u) {
    unsigned v = ((unsigned)u) << 16;
    return __builtin_bit_cast(float, v);
}
__device__ inline ushort f2bf(float f) {
    unsigned u = __builtin_bit_cast(unsigned, f);
    u += 0x7fffu + ((u >> 16) & 1u);
    return (ushort)(u >> 16);
}
__device__ inline void async_load16(const ushort* g, ushort* l) {
    __builtin_amdgcn_global_load_lds((const __attribute__((address_space(1))) void*)g,
                                     (__attribute__((address_space(3))) void*)l, 16, 0, 0);
}

// Single merged fp32->bf16 cast for all 5 tensors. 8 elems/thread.
// Ranges (blocks): hs 2048 | Wq 512 | Wk 512 | Wv 512 | Ws 128  => grid 3712
__global__ void cast_all(const float* __restrict__ hs, const float* __restrict__ Wq,
                         const float* __restrict__ Wk, const float* __restrict__ Wv,
                         const float* __restrict__ Ws,
                         ushort* __restrict__ dhs, ushort* __restrict__ dWq,
                         ushort* __restrict__ dWk, ushort* __restrict__ dWv,
                         ushort* __restrict__ dWs)
{
    int bid = blockIdx.x;
    const float* src; ushort* dst; int off;
    if (bid < 2048)      { src = hs; dst = dhs; off = bid; }
    else if (bid < 2560) { src = Wq; dst = dWq; off = bid - 2048; }
    else if (bid < 3072) { src = Wk; dst = dWk; off = bid - 2560; }
    else if (bid < 3584) { src = Wv; dst = dWv; off = bid - 3072; }
    else                 { src = Ws; dst = dWs; off = bid - 3584; }
    int i = (off * 256 + threadIdx.x) * 8;
    float4 a = *(const float4*)(src + i);
    float4 b = *(const float4*)(src + i + 4);
    union { ushort u[8]; float4 v; } o;
    o.u[0] = f2bf(a.x); o.u[1] = f2bf(a.y); o.u[2] = f2bf(a.z); o.u[3] = f2bf(a.w);
    o.u[4] = f2bf(b.x); o.u[5] = f2bf(b.y); o.u[6] = f2bf(b.z); o.u[7] = f2bf(b.w);
    *(float4*)(dst + i) = o.v;
}

// Fused QKVS projection. X:[4096,1024] bf16, W*:[N,1024] bf16 row-major, bias fp32.
// xb 0-7 -> Q (scaled 0.125*log2e), 8-15 -> K, 16-23 -> V (transposed to VtG[bh][d][s]),
// 24-25 -> S (sigmoid -> fp32 sb). LDS XOR chunk swizzle: chunk c of row r at slot c^(r&7).
__launch_bounds__(256, 4)
__global__ void fused_qkvs(const ushort* __restrict__ X,
                           const ushort* __restrict__ Wq, const ushort* __restrict__ Wk,
                           const ushort* __restrict__ Wv, const ushort* __restrict__ Ws,
                           const float* __restrict__ bq, const float* __restrict__ bk,
                           const float* __restrict__ bv, const float* __restrict__ bs,
                           ushort* __restrict__ Qb, ushort* __restrict__ Kb,
                           ushort* __restrict__ VtG, float* __restrict__ sb)
{
    __shared__ __align__(16) ushort Sm[128 * 136];   // epilogue scratch; aliases As/Bs
    ushort* As = Sm;                 // 128 rows x 64 cols (swizzled)
    ushort* Bs = Sm + 128 * 64;

    const int tid = threadIdx.x, w = tid >> 6, lane = tid & 63;
    const int l15 = lane & 15, quad = lane >> 4;
    const int lrow = lane >> 3;
    const int gchunk = ((lane & 7) ^ lrow) * 8;   // swizzled global chunk for staging

    const int wid = blockIdx.x;
    const int r8 = wid & 7, jj = wid >> 3;
    const int by = (jj & 3) * 8 + r8;    // 0..31
    const int xb = jj >> 2;              // 0..25
    const int m0 = by * 128;

    const ushort* W; const float* bias; int n0, mode;
    if (xb < 8)       { W = Wq; bias = bq; n0 = xb * 128;        mode = 1; }
    else if (xb < 16) { W = Wk; bias = bk; n0 = (xb - 8) * 128;  mode = 0; }
    else if (xb < 24) { W = Wv; bias = bv; n0 = (xb - 16) * 128; mode = 2; }
    else              { W = Ws; bias = bs; n0 = (xb - 24) * 128; mode = 3; }

    const int wm = (w >> 1) * 64, wn = (w & 1) * 64;

    f32x4 acc[4][4];
    for (int i = 0; i < 4; i++) for (int j = 0; j < 4; j++) acc[i][j] = (f32x4){0.f, 0.f, 0.f, 0.f};

    for (int k0 = 0; k0 < 1024; k0 += 64) {
        __syncthreads();
        for (int c = 0; c < 4; ++c) {
            int r = w * 32 + c * 8;
            async_load16(&X[(size_t)(m0 + r + lrow) * 1024 + k0 + gchunk], &As[r * 64]);
            async_load16(&W[(size_t)(n0 + r + lrow) * 1024 + k0 + gchunk], &Bs[r * 64]);
        }
        __syncthreads();
        for (int kk = 0; kk < 64; kk += 32) {
            const int csw = quad + (kk >> 3);
            bf16x8 a[4], b[4];
            for (int i = 0; i < 4; i++)
                a[i] = *(const bf16x8*)&As[(wm + i * 16 + l15) * 64 + ((csw ^ (l15 & 7)) * 8)];
            for (int j = 0; j < 4; j++)
                b[j] = *(const bf16x8*)&Bs[(wn + j * 16 + l15) * 64 + ((csw ^ (l15 & 7)) * 8)];
            for (int i = 0; i < 4; i++)
                for (int j = 0; j < 4; j++)
                    acc[i][j] = __builtin_amdgcn_mfma_f32_16x16x32_bf16(a[i], b[j], acc[i][j], 0, 0, 0);
        }
    }

    const float QSCALE = 0.125f * 1.44269504f;  // 1/sqrt(D) and ln->log2 folded into Q

    if (mode == 3) {
        for (int i = 0; i < 4; i++)
            for (int j = 0; j < 4; j++) {
                int gn = n0 + wn + j * 16 + l15;
                float bv_ = bias[gn];
                for (int r = 0; r < 4; r++) {
                    int gm = m0 + wm + i * 16 + quad * 4 + r;
                    float v = acc[i][j][r] + bv_;
                    float sg = 1.0f / (1.0f + exp2f(-v * 1.44269504f));
                    sb[(size_t)gm * 256 + gn] = sg * 0.1f + 0.95f;
                }
            }
        return;
    }

    __syncthreads();  // main loop done with As/Bs; Sm becomes epilogue scratch

    if (mode == 2) {
        for (int i = 0; i < 4; i++)
            for (int j = 0; j < 4; j++) {
                int gnl = wn + j * 16 + l15;
                float bv_ = bias[n0 + gnl];
                ushort4 pk;
                pk.x = f2bf(acc[i][j][0] + bv_);
                pk.y = f2bf(acc[i][j][1] + bv_);
                pk.z = f2bf(acc[i][j][2] + bv_);
                pk.w = f2bf(acc[i][j][3] + bv_);
                *(ushort4*)&Sm[gnl * 136 + wm + i * 16 + quad * 4] = pk;
            }
        __syncthreads();
        const int bb = m0 >> 11, sloc = m0 & 2047;
        for (int it = 0; it < 8; ++it) {
            int d = (tid >> 4) + it * 16;
            int s8 = (tid & 15) * 8;
            float4 v = *(float4*)&Sm[d * 136 + s8];
            int h = (n0 + d) >> 6, dd = d & 63;
            *(float4*)&VtG[(size_t)(bb * 16 + h) * 131072 + (size_t)dd * 2048 + sloc + s8] = v;
        }
    } else {
        for (int i = 0; i < 4; i++)
            for (int j = 0; j < 4; j++) {
                int gnl = wn + j * 16 + l15;
                float bv_ = bias[n0 + gnl];
                for (int r = 0; r < 4; r++) {
                    float v = acc[i][j][r] + bv_;
                    if (mode == 1) v *= QSCALE;
                    Sm[(wm + i * 16 + quad * 4 + r) * 136 + gnl] = f2bf(v);
                }
            }
        __syncthreads();
        ushort* dst = (mode == 1) ? Qb : Kb;
        for (int it = 0; it < 8; ++it) {
            int row = (tid >> 4) + it * 16, c = (tid & 15) * 8;
            *(float4*)&dst[(size_t)(m0 + row) * 1024 + n0 + c] = *(float4*)&Sm[row * 136 + c];
        }
    }
}

// Flash attention, no-max softmax (log2e folded into Q).
// Q:[4096,1024] bf16 (pre-scaled; groupwise s applied during Qs staging),
// K:[4096,1024] bf16, Vt:[32][64][2048] bf16, out fp32 [4096,1024].
// flat grid 512 (XCD-swizzled), block 256, no in-loop barriers.
// K/V B-frags are REGISTER double-buffered: set for iter kt+1 is loaded from
// global (L2-resident) before computing iter kt -> full-iteration prefetch distance.
__launch_bounds__(256, 2)
__global__ void attn_kernel(const ushort* __restrict__ Q, const ushort* __restrict__ K,
                            const ushort* __restrict__ Vt, const float* __restrict__ sb,
                            float* __restrict__ out)
{
    __shared__ __align__(16) ushort Qs[128 * 72];
    __shared__ __align__(16) ushort Ps[128 * 72];

    const int tid = threadIdx.x, w = tid >> 6, lane = tid & 63;
    const int l15 = lane & 15, quad = lane >> 4;

    // XCD swizzle: same bh (same K/V) -> same XCD
    const int wid = blockIdx.x;
    const int r8 = wid & 7, jj = wid >> 3;
    const int bh = (jj & 3) * 8 + r8;    // 0..31
    const int qx = jj >> 2;              // 0..15
    const int b = bh >> 4, h = bh & 15;
    const int q0 = qx * 128;
    const size_t rowbase = (size_t)b * 2048;
    const int cbase = h * 64;

    // stage Q tile (apply groupwise scale s; s index for col n is n>>2)
    for (int it = 0; it < 4; ++it) {
        int l = tid + it * 256;
        int r = l >> 3, c = (l & 7) * 8;
        union { float4 f; ushort u[8]; } uu, oo;
        uu.f = *(const float4*)&Q[(rowbase + q0 + r) * 1024 + cbase + c];
        const float* sp = &sb[(rowbase + q0 + r) * 256 + ((cbase + c) >> 2)];
        float s0 = sp[0], s1 = sp[1];
        for (int j = 0; j < 4; j++) oo.u[j] = f2bf(bf2f(uu.u[j]) * s0);
        for (int j = 4; j < 8; j++) oo.u[j] = f2bf(bf2f(uu.u[j]) * s1);
        *(float4*)&Qs[r * 72 + c] = oo.f;
    }
    __syncthreads();  // the only barrier

    // hoist loop-invariant Q A-frags to registers
    bf16x8 aq[2][2];  // [mt][kk2]
    for (int mt = 0; mt < 2; mt++)
        for (int kk2 = 0; kk2 < 2; kk2++)
            aq[mt][kk2] = *(const bf16x8*)&Qs[(w * 32 + mt * 16 + l15) * 72 + kk2 * 32 + quad * 8];

    const ushort* Kbase = K + rowbase * 1024 + cbase;         // K[key][d], stride 1024
    const ushort* Vbase = Vt + (size_t)bh * 131072;           // Vt[d][k], stride 2048

    float lsum[2][4];
    f32x4 o[2][4];
    for (int mt = 0; mt < 2; mt++) for (int r = 0; r < 4; r++) lsum[mt][r] = 0.f;
    for (int mt = 0; mt < 2; mt++) for (int nt = 0; nt < 4; nt++) o[mt][nt] = (f32x4){0.f, 0.f, 0.f, 0.f};

    bf16x8 kbA[2][4], vbA[2][4], kbB[2][4], vbB[2][4];

#define LOADF(KB, VB, KT)                                                                               \
    {                                                                                                   \
        const int k0_ = (KT) * 64;                                                                      \
        for (int kk2 = 0; kk2 < 2; kk2++)                                                               \
            for (int nt = 0; nt < 4; nt++) {                                                            \
                KB[kk2][nt] = *(const bf16x8*)&Kbase[(size_t)(k0_ + nt * 16 + l15) * 1024               \
                                                     + kk2 * 32 + quad * 8];                            \
                VB[kk2][nt] = *(const bf16x8*)&Vbase[(size_t)(nt * 16 + l15) * 2048                     \
                                                     + k0_ + kk2 * 32 + quad * 8];                      \
            }                                                                                           \
    }

#define STEP(KB, VB)                                                                                    \
    {                                                                                                   \
        f32x4 sacc[2][4];                                                                               \
        for (int mt = 0; mt < 2; mt++)                                                                  \
            for (int nt = 0; nt < 4; nt++) sacc[mt][nt] = (f32x4){0.f, 0.f, 0.f, 0.f};                  \
        for (int kk2 = 0; kk2 < 2; kk2++)                                                               \
            for (int mt = 0; mt < 2; mt++)                                                              \
                for (int nt = 0; nt < 4; nt++)                                                          \
                    sacc[mt][nt] = __builtin_amdgcn_mfma_f32_16x16x32_bf16(aq[mt][kk2], KB[kk2][nt],    \
                                                                           sacc[mt][nt], 0, 0, 0);      \
        for (int mt = 0; mt < 2; mt++)                                                                  \
            for (int nt = 0; nt < 4; nt++)                                                              \
                for (int r = 0; r < 4; r++) {                                                           \
                    float p = exp2f(sacc[mt][nt][r]);                                                   \
                    lsum[mt][r] += p;                                                                   \
                    unsigned u_ = __builtin_bit_cast(unsigned, p) + 0x8000u; /* round-half-up */        \
                    Ps[(w * 32 + mt * 16 + quad * 4 + r) * 72 + nt * 16 + l15] = (ushort)(u_ >> 16);    \
                }                                                                                       \
        for (int kk2 = 0; kk2 < 2; kk2++) {                                                             \
            bf16x8 a_[2];                                                                               \
            for (int mt = 0; mt < 2; mt++)                                                              \
                a_[mt] = *(const bf16x8*)&Ps[(w * 32 + mt * 16 + l15) * 72 + kk2 * 32 + quad * 8];      \
            for (int mt = 0; mt < 2; mt++)                                                              \
                for (int nt = 0; nt < 4; nt++)                                                          \
                    o[mt][nt] = __builtin_amdgcn_mfma_f32_16x16x32_bf16(a_[mt], VB[kk2][nt],            \
                                                                        o[mt][nt], 0, 0, 0);            \
        }                                                                                               \
    }

    LOADF(kbA, vbA, 0);
    for (int kt = 0; kt < 32; kt += 2) {
        LOADF(kbB, vbB, kt + 1);          // prefetch kt+1 while computing kt
        STEP(kbA, vbA);
        if (kt + 2 < 32) LOADF(kbA, vbA, kt + 2);   // prefetch kt+2 while computing kt+1
        STEP(kbB, vbB);
    }
#undef LOADF
#undef STEP

    for (int mt = 0; mt < 2; mt++)
        for (int r = 0; r < 4; r++) {
            float s = lsum[mt][r];
            for (int off = 1; off < 16; off <<= 1) s += __shfl_xor(s, off);
            lsum[mt][r] = s;
        }

    for (int mt = 0; mt < 2; mt++) {
        for (int r = 0; r < 4; r++) {
            float inv = 1.0f / lsum[mt][r];
            int q = q0 + w * 32 + mt * 16 + quad * 4 + r;
            size_t base = (rowbase + q) * 1024 + cbase;
            for (int nt = 0; nt < 4; nt++)
                out[base + nt * 16 + l15] = o[mt][nt][r] * inv;
        }
    }
}

extern "C" void kernel_launch(void* const* d_in, const int* in_sizes, int n_in,
                              void* d_out, int out_size, void* d_ws, size_t ws_size,
                              hipStream_t stream) {
    const float* hs = (const float*)d_in[0];
    const float* Wq = (const float*)d_in[1];
    const float* bq = (const float*)d_in[2];
    const float* Wk = (const float*)d_in[3];
    const float* bk = (const float*)d_in[4];
    const float* Wv = (const float*)d_in[5];
    const float* bv = (const float*)d_in[6];
    const float* Ws = (const float*)d_in[7];
    const float* bs = (const float*)d_in[8];
    float* outp = (float*)d_out;

    char* ws = (char*)d_ws;
    ushort* Qb    = (ushort*)(ws);                 //  8 MB
    ushort* Kb    = (ushort*)(ws + 8388608);       //  8 MB
    ushort* VtG   = (ushort*)(ws + 16777216);      //  8 MB (V transposed [bh][d][s])
    float*  sb    = (float* )(ws + 25165824);      //  4 MB
    ushort* hs_bf = (ushort*)(ws + 29360128);      //  8 MB
    ushort* Wq_bf = (ushort*)(ws + 37748736);      //  2 MB
    ushort* Wk_bf = (ushort*)(ws + 39845888);      //  2 MB
    ushort* Wv_bf = (ushort*)(ws + 41943040);      //  2 MB
    ushort* Ws_bf = (ushort*)(ws + 44040192);      // 0.5 MB -> total 44,564,480 B

    dim3 blk(256);
    cast_all<<<dim3(3712), blk, 0, stream>>>(hs, Wq, Wk, Wv, Ws,
                                             hs_bf, Wq_bf, Wk_bf, Wv_bf, Ws_bf);
    fused_qkvs<<<dim3(832), blk, 0, stream>>>(hs_bf, Wq_bf, Wk_bf, Wv_bf, Ws_bf,
                                              bq, bk, bv, bs, Qb, Kb, VtG, sb);
    attn_kernel<<<dim3(512), blk, 0, stream>>>(Qb, Kb, VtG, sb, outp);
}

// Round 8
// 189.470 us; speedup vs baseline: 1.4885x; 1.3357x over previous
//
#include <hip/hip_runtime.h>

typedef short bf16x8 __attribute__((ext_vector_type(8)));
typedef float f32x4 __attribute__((ext_vector_type(4)));

__device__ inline float bf2f(ushort u) {
    unsigned v = ((unsigned)u) << 16;
    return __builtin_bit_cast(float, v);
}
__device__ inline ushort f2bf(float f) {
    unsigned u = __builtin_bit_cast(unsigned, f);
    u += 0x7fffu + ((u >> 16) & 1u);
    return (ushort)(u >> 16);
}
__device__ inline void async_load16(const ushort* g, ushort* l) {
    __builtin_amdgcn_global_load_lds((const __attribute__((address_space(1))) void*)g,
                                     (__attribute__((address_space(3))) void*)l, 16, 0, 0);
}

// Single merged fp32->bf16 cast for all 5 tensors. 8 elems/thread.
// Ranges (blocks): hs 2048 | Wq 512 | Wk 512 | Wv 512 | Ws 128  => grid 3712
__global__ void cast_all(const float* __restrict__ hs, const float* __restrict__ Wq,
                         const float* __restrict__ Wk, const float* __restrict__ Wv,
                         const float* __restrict__ Ws,
                         ushort* __restrict__ dhs, ushort* __restrict__ dWq,
                         ushort* __restrict__ dWk, ushort* __restrict__ dWv,
                         ushort* __restrict__ dWs)
{
    int bid = blockIdx.x;
    const float* src; ushort* dst; int off;
    if (bid < 2048)      { src = hs; dst = dhs; off = bid; }
    else if (bid < 2560) { src = Wq; dst = dWq; off = bid - 2048; }
    else if (bid < 3072) { src = Wk; dst = dWk; off = bid - 2560; }
    else if (bid < 3584) { src = Wv; dst = dWv; off = bid - 3072; }
    else                 { src = Ws; dst = dWs; off = bid - 3584; }
    int i = (off * 256 + threadIdx.x) * 8;
    float4 a = *(const float4*)(src + i);
    float4 b = *(const float4*)(src + i + 4);
    union { ushort u[8]; float4 v; } o;
    o.u[0] = f2bf(a.x); o.u[1] = f2bf(a.y); o.u[2] = f2bf(a.z); o.u[3] = f2bf(a.w);
    o.u[4] = f2bf(b.x); o.u[5] = f2bf(b.y); o.u[6] = f2bf(b.z); o.u[7] = f2bf(b.w);
    *(float4*)(dst + i) = o.v;
}

// Fused QKVS projection. X:[4096,1024] bf16, W*:[N,1024] bf16 row-major, bias fp32.
// xb 0-7 -> Q (scaled 0.125*log2e), 8-15 -> K, 16-23 -> V (transposed to VtG[bh][d][s]),
// 24-25 -> S (sigmoid -> fp32 sb). LDS XOR chunk swizzle: chunk c of row r at slot c^(r&7).
__launch_bounds__(256, 4)
__global__ void fused_qkvs(const ushort* __restrict__ X,
                           const ushort* __restrict__ Wq, const ushort* __restrict__ Wk,
                           const ushort* __restrict__ Wv, const ushort* __restrict__ Ws,
                           const float* __restrict__ bq, const float* __restrict__ bk,
                           const float* __restrict__ bv, const float* __restrict__ bs,
                           ushort* __restrict__ Qb, ushort* __restrict__ Kb,
                           ushort* __restrict__ VtG, float* __restrict__ sb)
{
    __shared__ __align__(16) ushort Sm[128 * 136];   // epilogue scratch; aliases As/Bs
    ushort* As = Sm;                 // 128 rows x 64 cols (swizzled)
    ushort* Bs = Sm + 128 * 64;

    const int tid = threadIdx.x, w = tid >> 6, lane = tid & 63;
    const int l15 = lane & 15, quad = lane >> 4;
    const int lrow = lane >> 3;
    const int gchunk = ((lane & 7) ^ lrow) * 8;   // swizzled global chunk for staging

    const int wid = blockIdx.x;
    const int r8 = wid & 7, jj = wid >> 3;
    const int by = (jj & 3) * 8 + r8;    // 0..31
    const int xb = jj >> 2;              // 0..25
    const int m0 = by * 128;

    const ushort* W; const float* bias; int n0, mode;
    if (xb < 8)       { W = Wq; bias = bq; n0 = xb * 128;        mode = 1; }
    else if (xb < 16) { W = Wk; bias = bk; n0 = (xb - 8) * 128;  mode = 0; }
    else if (xb < 24) { W = Wv; bias = bv; n0 = (xb - 16) * 128; mode = 2; }
    else              { W = Ws; bias = bs; n0 = (xb - 24) * 128; mode = 3; }

    const int wm = (w >> 1) * 64, wn = (w & 1) * 64;

    f32x4 acc[4][4];
    for (int i = 0; i < 4; i++) for (int j = 0; j < 4; j++) acc[i][j] = (f32x4){0.f, 0.f, 0.f, 0.f};

    for (int k0 = 0; k0 < 1024; k0 += 64) {
        __syncthreads();
        for (int c = 0; c < 4; ++c) {
            int r = w * 32 + c * 8;
            async_load16(&X[(size_t)(m0 + r + lrow) * 1024 + k0 + gchunk], &As[r * 64]);
            async_load16(&W[(size_t)(n0 + r + lrow) * 1024 + k0 + gchunk], &Bs[r * 64]);
        }
        __syncthreads();
        for (int kk = 0; kk < 64; kk += 32) {
            const int csw = quad + (kk >> 3);
            bf16x8 a[4], b[4];
            for (int i = 0; i < 4; i++)
                a[i] = *(const bf16x8*)&As[(wm + i * 16 + l15) * 64 + ((csw ^ (l15 & 7)) * 8)];
            for (int j = 0; j < 4; j++)
                b[j] = *(const bf16x8*)&Bs[(wn + j * 16 + l15) * 64 + ((csw ^ (l15 & 7)) * 8)];
            for (int i = 0; i < 4; i++)
                for (int j = 0; j < 4; j++)
                    acc[i][j] = __builtin_amdgcn_mfma_f32_16x16x32_bf16(a[i], b[j], acc[i][j], 0, 0, 0);
        }
    }

    const float QSCALE = 0.125f * 1.44269504f;  // 1/sqrt(D) and ln->log2 folded into Q

    if (mode == 3) {
        for (int i = 0; i < 4; i++)
            for (int j = 0; j < 4; j++) {
                int gn = n0 + wn + j * 16 + l15;
                float bv_ = bias[gn];
                for (int r = 0; r < 4; r++) {
                    int gm = m0 + wm + i * 16 + quad * 4 + r;
                    float v = acc[i][j][r] + bv_;
                    float sg = 1.0f / (1.0f + exp2f(-v * 1.44269504f));
                    sb[(size_t)gm * 256 + gn] = sg * 0.1f + 0.95f;
                }
            }
        return;
    }

    __syncthreads();  // main loop done with As/Bs; Sm becomes epilogue scratch

    if (mode == 2) {
        for (int i = 0; i < 4; i++)
            for (int j = 0; j < 4; j++) {
                int gnl = wn + j * 16 + l15;
                float bv_ = bias[n0 + gnl];
                ushort4 pk;
                pk.x = f2bf(acc[i][j][0] + bv_);
                pk.y = f2bf(acc[i][j][1] + bv_);
                pk.z = f2bf(acc[i][j][2] + bv_);
                pk.w = f2bf(acc[i][j][3] + bv_);
                *(ushort4*)&Sm[gnl * 136 + wm + i * 16 + quad * 4] = pk;
            }
        __syncthreads();
        const int bb = m0 >> 11, sloc = m0 & 2047;
        for (int it = 0; it < 8; ++it) {
            int d = (tid >> 4) + it * 16;
            int s8 = (tid & 15) * 8;
            float4 v = *(float4*)&Sm[d * 136 + s8];
            int h = (n0 + d) >> 6, dd = d & 63;
            *(float4*)&VtG[(size_t)(bb * 16 + h) * 131072 + (size_t)dd * 2048 + sloc + s8] = v;
        }
    } else {
        for (int i = 0; i < 4; i++)
            for (int j = 0; j < 4; j++) {
                int gnl = wn + j * 16 + l15;
                float bv_ = bias[n0 + gnl];
                for (int r = 0; r < 4; r++) {
                    float v = acc[i][j][r] + bv_;
                    if (mode == 1) v *= QSCALE;
                    Sm[(wm + i * 16 + quad * 4 + r) * 136 + gnl] = f2bf(v);
                }
            }
        __syncthreads();
        ushort* dst = (mode == 1) ? Qb : Kb;
        for (int it = 0; it < 8; ++it) {
            int row = (tid >> 4) + it * 16, c = (tid & 15) * 8;
            *(float4*)&dst[(size_t)(m0 + row) * 1024 + n0 + c] = *(float4*)&Sm[row * 136 + c];
        }
    }
}

// Flash attention, no-max softmax (log2e folded into Q).
// Round-5 skeleton (async LDS-staged dbuf K/V, 1 barrier/STEP - HW-guaranteed prefetch
// distance) + hoisted Q frags + base-pointer Ps writes + cheap pack + half-split PV.
// Q:[4096,1024] bf16 (pre-scaled; groupwise s applied during Qs staging),
// K:[4096,1024] bf16, Vt:[32][64][2048] bf16, out fp32 [4096,1024].
// flat grid 512 (XCD-swizzled), block 256.
__launch_bounds__(256, 2)
__global__ void attn_kernel(const ushort* __restrict__ Q, const ushort* __restrict__ K,
                            const ushort* __restrict__ Vt, const float* __restrict__ sb,
                            float* __restrict__ out)
{
    __shared__ __align__(16) ushort Qs[128 * 72];
    __shared__ __align__(16) ushort Ps[128 * 72];
    __shared__ __align__(16) ushort Ks0[64 * 64];
    __shared__ __align__(16) ushort Ks1[64 * 64];
    __shared__ __align__(16) ushort Vs0[64 * 64];
    __shared__ __align__(16) ushort Vs1[64 * 64];

    const int tid = threadIdx.x, w = tid >> 6, lane = tid & 63;
    const int l15 = lane & 15, quad = lane >> 4;
    const int lrow = lane >> 3;
    const int gchunk = ((lane & 7) ^ lrow) * 8;   // swizzled global chunk for staging

    // XCD swizzle: same bh (same K/V) -> same XCD
    const int wid = blockIdx.x;
    const int r8 = wid & 7, jj = wid >> 3;
    const int bh = (jj & 3) * 8 + r8;    // 0..31
    const int qx = jj >> 2;              // 0..15
    const int b = bh >> 4, h = bh & 15;
    const int q0 = qx * 128;
    const size_t rowbase = (size_t)b * 2048;
    const int cbase = h * 64;

    // stage Q tile (apply groupwise scale s; s index for col n is n>>2)
    for (int it = 0; it < 4; ++it) {
        int l = tid + it * 256;
        int r = l >> 3, c = (l & 7) * 8;
        union { float4 f; ushort u[8]; } uu, oo;
        uu.f = *(const float4*)&Q[(rowbase + q0 + r) * 1024 + cbase + c];
        const float* sp = &sb[(rowbase + q0 + r) * 256 + ((cbase + c) >> 2)];
        float s0 = sp[0], s1 = sp[1];
        for (int j = 0; j < 4; j++) oo.u[j] = f2bf(bf2f(uu.u[j]) * s0);
        for (int j = 4; j < 8; j++) oo.u[j] = f2bf(bf2f(uu.u[j]) * s1);
        *(float4*)&Qs[r * 72 + c] = oo.f;
    }

    // prefetch K/V tile 0 into buffer 0 (swizzled)
    for (int c = 0; c < 2; ++c) {
        int r = w * 16 + c * 8;
        async_load16(&K[(rowbase + r + lrow) * 1024 + cbase + gchunk], &Ks0[r * 64]);
        async_load16(&Vt[(size_t)bh * 131072 + (size_t)(r + lrow) * 2048 + gchunk], &Vs0[r * 64]);
    }
    __syncthreads();   // drains lgkm+vmcnt: Qs and tile0 resident

    // hoist loop-invariant Q A-frags to registers
    bf16x8 aq[2][2];  // [mt][kk2]
    for (int mt = 0; mt < 2; mt++)
        for (int kk2 = 0; kk2 < 2; kk2++)
            aq[mt][kk2] = *(const bf16x8*)&Qs[(w * 32 + mt * 16 + l15) * 72 + kk2 * 32 + quad * 8];

    // Ps write base: element (mt,r,nt) at pbase[mt*1152 + r*72 + nt*16] (imm offsets)
    ushort* pbase = &Ps[(w * 32 + quad * 4) * 72 + l15];

    float lsum[2][4];
    f32x4 o[2][4];
    for (int mt = 0; mt < 2; mt++) for (int r = 0; r < 4; r++) lsum[mt][r] = 0.f;
    for (int mt = 0; mt < 2; mt++) for (int nt = 0; nt < 4; nt++) o[mt][nt] = (f32x4){0.f, 0.f, 0.f, 0.f};

#define ATTN_STEP(KC, VC, KN, VN, KT, PREFETCH)                                                         \
    {                                                                                                   \
        __syncthreads(); /* vmcnt drained: tile KT resident; buffers KN/VN free */                      \
        if (PREFETCH) {                                                                                 \
            int nk = (KT) + 1;                                                                          \
            for (int c = 0; c < 2; ++c) {                                                               \
                int r = w * 16 + c * 8;                                                                 \
                async_load16(&K[(rowbase + nk * 64 + r + lrow) * 1024 + cbase + gchunk], &KN[r * 64]);  \
                async_load16(&Vt[(size_t)bh * 131072 + (size_t)(r + lrow) * 2048 + nk * 64 + gchunk],   \
                             &VN[r * 64]);                                                              \
            }                                                                                           \
        }                                                                                               \
        bf16x8 kb[2][4], vb[2][4];                                                                      \
        for (int kk2 = 0; kk2 < 2; kk2++)                                                               \
            for (int nt = 0; nt < 4; nt++) {                                                            \
                const int csw = (((quad + kk2 * 4)) ^ (l15 & 7)) * 8;                                   \
                kb[kk2][nt] = *(const bf16x8*)&KC[(nt * 16 + l15) * 64 + csw];                          \
                vb[kk2][nt] = *(const bf16x8*)&VC[(nt * 16 + l15) * 64 + csw];                          \
            }                                                                                           \
        f32x4 sacc[2][4];                                                                               \
        for (int mt = 0; mt < 2; mt++)                                                                  \
            for (int nt = 0; nt < 4; nt++) sacc[mt][nt] = (f32x4){0.f, 0.f, 0.f, 0.f};                  \
        for (int kk2 = 0; kk2 < 2; kk2++)                                                               \
            for (int mt = 0; mt < 2; mt++)                                                              \
                for (int nt = 0; nt < 4; nt++)                                                          \
                    sacc[mt][nt] = __builtin_amdgcn_mfma_f32_16x16x32_bf16(aq[mt][kk2], kb[kk2][nt],    \
                                                                           sacc[mt][nt], 0, 0, 0);      \
        for (int half = 0; half < 2; half++) {                                                          \
            for (int mt = 0; mt < 2; mt++)                                                              \
                for (int nt = 2 * half; nt < 2 * half + 2; nt++)                                        \
                    for (int r = 0; r < 4; r++) {                                                       \
                        float p = exp2f(sacc[mt][nt][r]);                                               \
                        lsum[mt][r] += p;                                                               \
                        unsigned u_ = __builtin_bit_cast(unsigned, p) + 0x8000u;                        \
                        pbase[mt * 1152 + r * 72 + nt * 16] = (ushort)(u_ >> 16);                       \
                    }                                                                                   \
            bf16x8 a_[2];                                                                               \
            for (int mt = 0; mt < 2; mt++)                                                              \
                a_[mt] = *(const bf16x8*)&Ps[(w * 32 + mt * 16 + l15) * 72 + half * 32 + quad * 8];     \
            for (int mt = 0; mt < 2; mt++)                                                              \
                for (int nt = 0; nt < 4; nt++)                                                          \
                    o[mt][nt] = __builtin_amdgcn_mfma_f32_16x16x32_bf16(a_[mt], vb[half][nt],           \
                                                                        o[mt][nt], 0, 0, 0);            \
        }                                                                                               \
    }

    for (int kt = 0; kt < 32; kt += 2) {
        ATTN_STEP(Ks0, Vs0, Ks1, Vs1, kt, 1);
        ATTN_STEP(Ks1, Vs1, Ks0, Vs0, kt + 1, (kt + 2 < 32));
    }
#undef ATTN_STEP

    for (int mt = 0; mt < 2; mt++)
        for (int r = 0; r < 4; r++) {
            float s = lsum[mt][r];
            for (int off = 1; off < 16; off <<= 1) s += __shfl_xor(s, off);
            lsum[mt][r] = s;
        }

    for (int mt = 0; mt < 2; mt++) {
        for (int r = 0; r < 4; r++) {
            float inv = 1.0f / lsum[mt][r];
            int q = q0 + w * 32 + mt * 16 + quad * 4 + r;
            size_t base = (rowbase + q) * 1024 + cbase;
            for (int nt = 0; nt < 4; nt++)
                out[base + nt * 16 + l15] = o[mt][nt][r] * inv;
        }
    }
}

extern "C" void kernel_launch(void* const* d_in, const int* in_sizes, int n_in,
                              void* d_out, int out_size, void* d_ws, size_t ws_size,
                              hipStream_t stream) {
    const float* hs = (const float*)d_in[0];
    const float* Wq = (const float*)d_in[1];
    const float* bq = (const float*)d_in[2];
    const float* Wk = (const float*)d_in[3];
    const float* bk = (const float*)d_in[4];
    const float* Wv = (const float*)d_in[5];
    const float* bv = (const float*)d_in[6];
    const float* Ws = (const float*)d_in[7];
    const float* bs = (const float*)d_in[8];
    float* outp = (float*)d_out;

    char* ws = (char*)d_ws;
    ushort* Qb    = (ushort*)(ws);                 //  8 MB
    ushort* Kb    = (ushort*)(ws + 8388608);       //  8 MB
    ushort* VtG   = (ushort*)(ws + 16777216);      //  8 MB (V transposed [bh][d][s])
    float*  sb    = (float* )(ws + 25165824);      //  4 MB
    ushort* hs_bf = (ushort*)(ws + 29360128);      //  8 MB
    ushort* Wq_bf = (ushort*)(ws + 37748736);      //  2 MB
    ushort* Wk_bf = (ushort*)(ws + 39845888);      //  2 MB
    ushort* Wv_bf = (ushort*)(ws + 41943040);      //  2 MB
    ushort* Ws_bf = (ushort*)(ws + 44040192);      // 0.5 MB -> total 44,564,480 B

    dim3 blk(256);
    cast_all<<<dim3(3712), blk, 0, stream>>>(hs, Wq, Wk, Wv, Ws,
                                             hs_bf, Wq_bf, Wk_bf, Wv_bf, Ws_bf);
    fused_qkvs<<<dim3(832), blk, 0, stream>>>(hs_bf, Wq_bf, Wk_bf, Wv_bf, Ws_bf,
                                              bq, bk, bv, bs, Qb, Kb, VtG, sb);
    attn_kernel<<<dim3(512), blk, 0, stream>>>(Qb, Kb, VtG, sb, outp);
}

// Round 9
// 186.253 us; speedup vs baseline: 1.5142x; 1.0173x over previous
//
#include <hip/hip_runtime.h>

typedef short bf16x8 __attribute__((ext_vector_type(8)));
typedef float f32x4 __attribute__((ext_vector_type(4)));

__device__ inline float bf2f(ushort u) {
    unsigned v = ((unsigned)u) << 16;
    return __builtin_bit_cast(float, v);
}
__device__ inline ushort f2bf(float f) {
    unsigned u = __builtin_bit_cast(unsigned, f);
    u += 0x7fffu + ((u >> 16) & 1u);
    return (ushort)(u >> 16);
}
__device__ inline void async_load16(const ushort* g, ushort* l) {
    __builtin_amdgcn_global_load_lds((const __attribute__((address_space(1))) void*)g,
                                     (__attribute__((address_space(3))) void*)l, 16, 0, 0);
}

// Single merged fp32->bf16 cast for all 5 tensors. 8 elems/thread.
__global__ void cast_all(const float* __restrict__ hs, const float* __restrict__ Wq,
                         const float* __restrict__ Wk, const float* __restrict__ Wv,
                         const float* __restrict__ Ws,
                         ushort* __restrict__ dhs, ushort* __restrict__ dWq,
                         ushort* __restrict__ dWk, ushort* __restrict__ dWv,
                         ushort* __restrict__ dWs)
{
    int bid = blockIdx.x;
    const float* src; ushort* dst; int off;
    if (bid < 2048)      { src = hs; dst = dhs; off = bid; }
    else if (bid < 2560) { src = Wq; dst = dWq; off = bid - 2048; }
    else if (bid < 3072) { src = Wk; dst = dWk; off = bid - 2560; }
    else if (bid < 3584) { src = Wv; dst = dWv; off = bid - 3072; }
    else                 { src = Ws; dst = dWs; off = bid - 3584; }
    int i = (off * 256 + threadIdx.x) * 8;
    float4 a = *(const float4*)(src + i);
    float4 b = *(const float4*)(src + i + 4);
    union { ushort u[8]; float4 v; } o;
    o.u[0] = f2bf(a.x); o.u[1] = f2bf(a.y); o.u[2] = f2bf(a.z); o.u[3] = f2bf(a.w);
    o.u[4] = f2bf(b.x); o.u[5] = f2bf(b.y); o.u[6] = f2bf(b.z); o.u[7] = f2bf(b.w);
    *(float4*)(dst + i) = o.v;
}

// Fused QKVS projection (unchanged from r8). X:[4096,1024] bf16, W*:[N,1024] bf16, bias fp32.
// xb 0-7 -> Q (scaled 0.125*log2e), 8-15 -> K, 16-23 -> V (transposed to VtG[bh][d][s]),
// 24-25 -> S (sigmoid -> fp32 sb). LDS XOR chunk swizzle: chunk c of row r at slot c^(r&7).
__launch_bounds__(256, 4)
__global__ void fused_qkvs(const ushort* __restrict__ X,
                           const ushort* __restrict__ Wq, const ushort* __restrict__ Wk,
                           const ushort* __restrict__ Wv, const ushort* __restrict__ Ws,
                           const float* __restrict__ bq, const float* __restrict__ bk,
                           const float* __restrict__ bv, const float* __restrict__ bs,
                           ushort* __restrict__ Qb, ushort* __restrict__ Kb,
                           ushort* __restrict__ VtG, float* __restrict__ sb)
{
    __shared__ __align__(16) ushort Sm[128 * 136];
    ushort* As = Sm;
    ushort* Bs = Sm + 128 * 64;

    const int tid = threadIdx.x, w = tid >> 6, lane = tid & 63;
    const int l15 = lane & 15, quad = lane >> 4;
    const int lrow = lane >> 3;
    const int gchunk = ((lane & 7) ^ lrow) * 8;

    const int wid = blockIdx.x;
    const int r8 = wid & 7, jj = wid >> 3;
    const int by = (jj & 3) * 8 + r8;
    const int xb = jj >> 2;
    const int m0 = by * 128;

    const ushort* W; const float* bias; int n0, mode;
    if (xb < 8)       { W = Wq; bias = bq; n0 = xb * 128;        mode = 1; }
    else if (xb < 16) { W = Wk; bias = bk; n0 = (xb - 8) * 128;  mode = 0; }
    else if (xb < 24) { W = Wv; bias = bv; n0 = (xb - 16) * 128; mode = 2; }
    else              { W = Ws; bias = bs; n0 = (xb - 24) * 128; mode = 3; }

    const int wm = (w >> 1) * 64, wn = (w & 1) * 64;

    f32x4 acc[4][4];
    for (int i = 0; i < 4; i++) for (int j = 0; j < 4; j++) acc[i][j] = (f32x4){0.f, 0.f, 0.f, 0.f};

    for (int k0 = 0; k0 < 1024; k0 += 64) {
        __syncthreads();
        for (int c = 0; c < 4; ++c) {
            int r = w * 32 + c * 8;
            async_load16(&X[(size_t)(m0 + r + lrow) * 1024 + k0 + gchunk], &As[r * 64]);
            async_load16(&W[(size_t)(n0 + r + lrow) * 1024 + k0 + gchunk], &Bs[r * 64]);
        }
        __syncthreads();
        for (int kk = 0; kk < 64; kk += 32) {
            const int csw = quad + (kk >> 3);
            bf16x8 a[4], b[4];
            for (int i = 0; i < 4; i++)
                a[i] = *(const bf16x8*)&As[(wm + i * 16 + l15) * 64 + ((csw ^ (l15 & 7)) * 8)];
            for (int j = 0; j < 4; j++)
                b[j] = *(const bf16x8*)&Bs[(wn + j * 16 + l15) * 64 + ((csw ^ (l15 & 7)) * 8)];
            for (int i = 0; i < 4; i++)
                for (int j = 0; j < 4; j++)
                    acc[i][j] = __builtin_amdgcn_mfma_f32_16x16x32_bf16(a[i], b[j], acc[i][j], 0, 0, 0);
        }
    }

    const float QSCALE = 0.125f * 1.44269504f;

    if (mode == 3) {
        for (int i = 0; i < 4; i++)
            for (int j = 0; j < 4; j++) {
                int gn = n0 + wn + j * 16 + l15;
                float bv_ = bias[gn];
                for (int r = 0; r < 4; r++) {
                    int gm = m0 + wm + i * 16 + quad * 4 + r;
                    float v = acc[i][j][r] + bv_;
                    float sg = 1.0f / (1.0f + exp2f(-v * 1.44269504f));
                    sb[(size_t)gm * 256 + gn] = sg * 0.1f + 0.95f;
                }
            }
        return;
    }

    __syncthreads();

    if (mode == 2) {
        for (int i = 0; i < 4; i++)
            for (int j = 0; j < 4; j++) {
                int gnl = wn + j * 16 + l15;
                float bv_ = bias[n0 + gnl];
                ushort4 pk;
                pk.x = f2bf(acc[i][j][0] + bv_);
                pk.y = f2bf(acc[i][j][1] + bv_);
                pk.z = f2bf(acc[i][j][2] + bv_);
                pk.w = f2bf(acc[i][j][3] + bv_);
                *(ushort4*)&Sm[gnl * 136 + wm + i * 16 + quad * 4] = pk;
            }
        __syncthreads();
        const int bb = m0 >> 11, sloc = m0 & 2047;
        for (int it = 0; it < 8; ++it) {
            int d = (tid >> 4) + it * 16;
            int s8 = (tid & 15) * 8;
            float4 v = *(float4*)&Sm[d * 136 + s8];
            int h = (n0 + d) >> 6, dd = d & 63;
            *(float4*)&VtG[(size_t)(bb * 16 + h) * 131072 + (size_t)dd * 2048 + sloc + s8] = v;
        }
    } else {
        for (int i = 0; i < 4; i++)
            for (int j = 0; j < 4; j++) {
                int gnl = wn + j * 16 + l15;
                float bv_ = bias[n0 + gnl];
                for (int r = 0; r < 4; r++) {
                    float v = acc[i][j][r] + bv_;
                    if (mode == 1) v *= QSCALE;
                    Sm[(wm + i * 16 + quad * 4 + r) * 136 + gnl] = f2bf(v);
                }
            }
        __syncthreads();
        ushort* dst = (mode == 1) ? Qb : Kb;
        for (int it = 0; it < 8; ++it) {
            int row = (tid >> 4) + it * 16, c = (tid & 15) * 8;
            *(float4*)&dst[(size_t)(m0 + row) * 1024 + n0 + c] = *(float4*)&Sm[row * 136 + c];
        }
    }
}

// Flash attention v9: S^T formulation (K as MFMA-A, Q as MFMA-B) so each lane holds
// 4 consecutive keys of one q-row -> b64 P-writes + perm-pack. No per-STEP sacc
// zero-init (accumulate vs persistent zero vector). Qs aliased onto K/V dbuf region;
// Ps is a swizzled per-wave 32x64 tile. LDS 48KB -> 3 blocks/CU.
__launch_bounds__(256, 3)
__global__ void attn_kernel(const ushort* __restrict__ Q, const ushort* __restrict__ K,
                            const ushort* __restrict__ Vt, const float* __restrict__ sb,
                            float* __restrict__ out)
{
    __shared__ __align__(16) ushort SmA[4 * 64 * 64];   // 32KB: Ks0|Ks1|Vs0|Vs1 (Qs aliased)
    __shared__ __align__(16) ushort Ps[4 * 32 * 64];    // 16KB: per-wave 32x64, chunk-swizzled
    ushort* Ks0 = SmA;
    ushort* Ks1 = SmA + 4096;
    ushort* Vs0 = SmA + 8192;
    ushort* Vs1 = SmA + 12288;
    ushort* Qs  = SmA;                                   // 128*72 = 18432B, dead after hoist

    const int tid = threadIdx.x, w = tid >> 6, lane = tid & 63;
    const int l15 = lane & 15, quad = lane >> 4;
    const int lrow = lane >> 3;
    const int gchunk = ((lane & 7) ^ lrow) * 8;

    // XCD swizzle: same bh (same K/V) -> same XCD
    const int wid = blockIdx.x;
    const int r8 = wid & 7, jj = wid >> 3;
    const int bh = (jj & 3) * 8 + r8;
    const int qx = jj >> 2;
    const int b = bh >> 4, h = bh & 15;
    const int q0 = qx * 128;
    const size_t rowbase = (size_t)b * 2048;
    const int cbase = h * 64;

    // stage Q tile (apply groupwise scale s)
    for (int it = 0; it < 4; ++it) {
        int l = tid + it * 256;
        int r = l >> 3, c = (l & 7) * 8;
        union { float4 f; ushort u[8]; } uu, oo;
        uu.f = *(const float4*)&Q[(rowbase + q0 + r) * 1024 + cbase + c];
        const float* sp = &sb[(rowbase + q0 + r) * 256 + ((cbase + c) >> 2)];
        float s0 = sp[0], s1 = sp[1];
        for (int j = 0; j < 4; j++) oo.u[j] = f2bf(bf2f(uu.u[j]) * s0);
        for (int j = 4; j < 8; j++) oo.u[j] = f2bf(bf2f(uu.u[j]) * s1);
        *(float4*)&Qs[r * 72 + c] = oo.f;
    }
    __syncthreads();

    // hoist loop-invariant Q frags (used as MFMA B-operand: lane l15 = q-row = n)
    bf16x8 aq[2][2];  // [mt][kk2]
    for (int mt = 0; mt < 2; mt++)
        for (int kk2 = 0; kk2 < 2; kk2++)
            aq[mt][kk2] = *(const bf16x8*)&Qs[(w * 32 + mt * 16 + l15) * 72 + kk2 * 32 + quad * 8];
    __syncthreads();   // all waves' ds_reads of Qs drained; region reusable for K/V

    // prefetch K/V tile 0 into buffer 0 (over the dead Qs region)
    for (int c = 0; c < 2; ++c) {
        int r = w * 16 + c * 8;
        async_load16(&K[(rowbase + r + lrow) * 1024 + cbase + gchunk], &Ks0[r * 64]);
        async_load16(&Vt[(size_t)bh * 131072 + (size_t)(r + lrow) * 2048 + gchunk], &Vs0[r * 64]);
    }

    // Ps addressing (chunk-swizzled by row&7 = l15&7):
    // write (mt,kt2): elem = w*2048 + mt*1024 + l15*64 + ((kt2*2+(quad>>1))^(l15&7))*8 + (quad&1)*4
    // read  (mt,half): elem = w*2048 + mt*1024 + l15*64 + ((half*4+quad)^(l15&7))*8
    ushort* pw = &Ps[w * 2048 + l15 * 64 + ((quad >> 1) ^ (l15 & 7) & 1 ? 0 : 0)]; (void)pw;
    const int wrbase = w * 2048 + l15 * 64 + (quad & 1) * 4;
    const int rdbase = w * 2048 + l15 * 64;

    float lsum[2] = {0.f, 0.f};
    f32x4 o[2][4];
    for (int mt = 0; mt < 2; mt++) for (int nt = 0; nt < 4; nt++) o[mt][nt] = (f32x4){0.f, 0.f, 0.f, 0.f};
    const f32x4 z4 = (f32x4){0.f, 0.f, 0.f, 0.f};

#define ATTN_STEP(KC, VC, KN, VN, KT, PREFETCH)                                                         \
    {                                                                                                   \
        __syncthreads(); /* vmcnt drained: tile KT resident; buffers KN/VN free */                      \
        if (PREFETCH) {                                                                                 \
            int nk = (KT) + 1;                                                                          \
            for (int c = 0; c < 2; ++c) {                                                               \
                int r = w * 16 + c * 8;                                                                 \
                async_load16(&K[(rowbase + nk * 64 + r + lrow) * 1024 + cbase + gchunk], &KN[r * 64]);  \
                async_load16(&Vt[(size_t)bh * 131072 + (size_t)(r + lrow) * 2048 + nk * 64 + gchunk],   \
                             &VN[r * 64]);                                                              \
            }                                                                                           \
        }                                                                                               \
        bf16x8 kb[2][4], vb[2][4];                                                                      \
        for (int kk2 = 0; kk2 < 2; kk2++)                                                               \
            for (int nt = 0; nt < 4; nt++) {                                                            \
                const int csw = ((quad + kk2 * 4) ^ (l15 & 7)) * 8;                                     \
                kb[kk2][nt] = *(const bf16x8*)&KC[(nt * 16 + l15) * 64 + csw];                          \
                vb[kk2][nt] = *(const bf16x8*)&VC[(nt * 16 + l15) * 64 + csw];                          \
            }                                                                                           \
        /* S^T: A = K frag (m=key), B = Q frag (n=q-row); no per-STEP zero-init */                      \
        f32x4 st[2][4];                                                                                 \
        for (int mt = 0; mt < 2; mt++)                                                                  \
            for (int kt2 = 0; kt2 < 4; kt2++) {                                                         \
                st[mt][kt2] = __builtin_amdgcn_mfma_f32_16x16x32_bf16(kb[0][kt2], aq[mt][0], z4, 0, 0, 0); \
                st[mt][kt2] = __builtin_amdgcn_mfma_f32_16x16x32_bf16(kb[1][kt2], aq[mt][1],            \
                                                                      st[mt][kt2], 0, 0, 0);            \
            }                                                                                           \
        for (int mt = 0; mt < 2; mt++)                                                                  \
            for (int kt2 = 0; kt2 < 4; kt2++) {                                                         \
                float p0 = exp2f(st[mt][kt2][0]);                                                       \
                float p1 = exp2f(st[mt][kt2][1]);                                                       \
                float p2 = exp2f(st[mt][kt2][2]);                                                       \
                float p3 = exp2f(st[mt][kt2][3]);                                                       \
                lsum[mt] += (p0 + p1) + (p2 + p3);                                                      \
                unsigned d0 = __builtin_amdgcn_perm(__builtin_bit_cast(unsigned, p1) + 0x8000u,         \
                                                    __builtin_bit_cast(unsigned, p0) + 0x8000u,         \
                                                    0x07060302u);                                       \
                unsigned d1 = __builtin_amdgcn_perm(__builtin_bit_cast(unsigned, p3) + 0x8000u,         \
                                                    __builtin_bit_cast(unsigned, p2) + 0x8000u,         \
                                                    0x07060302u);                                       \
                uint2 pk; pk.x = d0; pk.y = d1;                                                         \
                *(uint2*)&Ps[wrbase + mt * 1024 + (((kt2 * 2 + (quad >> 1)) ^ (l15 & 7)) * 8)] = pk;    \
            }                                                                                           \
        /* O += P @ V (Ps strip wave-private; lgkmcnt ordering suffices) */                             \
        for (int half = 0; half < 2; half++) {                                                          \
            bf16x8 a_[2];                                                                               \
            for (int mt = 0; mt < 2; mt++)                                                              \
                a_[mt] = *(const bf16x8*)&Ps[rdbase + mt * 1024 + (((half * 4 + quad) ^ (l15 & 7)) * 8)];\
            for (int mt = 0; mt < 2; mt++)                                                              \
                for (int nt = 0; nt < 4; nt++)                                                          \
                    o[mt][nt] = __builtin_amdgcn_mfma_f32_16x16x32_bf16(a_[mt], vb[half][nt],           \
                                                                        o[mt][nt], 0, 0, 0);            \
        }                                                                                               \
    }

    for (int kt = 0; kt < 32; kt += 2) {
        ATTN_STEP(Ks0, Vs0, Ks1, Vs1, kt, 1);
        ATTN_STEP(Ks1, Vs1, Ks0, Vs0, kt + 1, (kt + 2 < 32));
    }
#undef ATTN_STEP

    // finalize row sums: quads hold disjoint key subsets for q-row l15 -> xor-reduce
    float inv[2];
    for (int mt = 0; mt < 2; mt++) {
        float s = lsum[mt];
        s += __shfl_xor(s, 16);
        s += __shfl_xor(s, 32);
        inv[mt] = 1.0f / s;   // valid for q-row l15 (all lanes)
    }

    for (int mt = 0; mt < 2; mt++) {
        for (int r = 0; r < 4; r++) {
            float iv = __shfl(inv[mt], quad * 4 + r);   // inv for q-row quad*4+r
            int q = q0 + w * 32 + mt * 16 + quad * 4 + r;
            size_t base = (rowbase + q) * 1024 + cbase;
            for (int nt = 0; nt < 4; nt++)
                out[base + nt * 16 + l15] = o[mt][nt][r] * iv;
        }
    }
}

extern "C" void kernel_launch(void* const* d_in, const int* in_sizes, int n_in,
                              void* d_out, int out_size, void* d_ws, size_t ws_size,
                              hipStream_t stream) {
    const float* hs = (const float*)d_in[0];
    const float* Wq = (const float*)d_in[1];
    const float* bq = (const float*)d_in[2];
    const float* Wk = (const float*)d_in[3];
    const float* bk = (const float*)d_in[4];
    const float* Wv = (const float*)d_in[5];
    const float* bv = (const float*)d_in[6];
    const float* Ws = (const float*)d_in[7];
    const float* bs = (const float*)d_in[8];
    float* outp = (float*)d_out;

    char* ws = (char*)d_ws;
    ushort* Qb    = (ushort*)(ws);                 //  8 MB
    ushort* Kb    = (ushort*)(ws + 8388608);       //  8 MB
    ushort* VtG   = (ushort*)(ws + 16777216);      //  8 MB (V transposed [bh][d][s])
    float*  sb    = (float* )(ws + 25165824);      //  4 MB
    ushort* hs_bf = (ushort*)(ws + 29360128);      //  8 MB
    ushort* Wq_bf = (ushort*)(ws + 37748736);      //  2 MB
    ushort* Wk_bf = (ushort*)(ws + 39845888);      //  2 MB
    ushort* Wv_bf = (ushort*)(ws + 41943040);      //  2 MB
    ushort* Ws_bf = (ushort*)(ws + 44040192);      // 0.5 MB -> total 44,564,480 B

    dim3 blk(256);
    cast_all<<<dim3(3712), blk, 0, stream>>>(hs, Wq, Wk, Wv, Ws,
                                             hs_bf, Wq_bf, Wk_bf, Wv_bf, Ws_bf);
    fused_qkvs<<<dim3(832), blk, 0, stream>>>(hs_bf, Wq_bf, Wk_bf, Wv_bf, Ws_bf,
                                              bq, bk, bv, bs, Qb, Kb, VtG, sb);
    attn_kernel<<<dim3(512), blk, 0, stream>>>(Qb, Kb, VtG, sb, outp);
}

// Round 10
// 180.313 us; speedup vs baseline: 1.5641x; 1.0329x over previous
//
#include <hip/hip_runtime.h>

typedef short bf16x8 __attribute__((ext_vector_type(8)));
typedef float f32x4 __attribute__((ext_vector_type(4)));

__device__ inline float bf2f(ushort u) {
    unsigned v = ((unsigned)u) << 16;
    return __builtin_bit_cast(float, v);
}
__device__ inline ushort f2bf(float f) {
    unsigned u = __builtin_bit_cast(unsigned, f);
    u += 0x7fffu + ((u >> 16) & 1u);
    return (ushort)(u >> 16);
}
__device__ inline void async_load16(const ushort* g, ushort* l) {
    __builtin_amdgcn_global_load_lds((const __attribute__((address_space(1))) void*)g,
                                     (__attribute__((address_space(3))) void*)l, 16, 0, 0);
}

// Single merged fp32->bf16 cast for all 5 tensors. 8 elems/thread.
__global__ void cast_all(const float* __restrict__ hs, const float* __restrict__ Wq,
                         const float* __restrict__ Wk, const float* __restrict__ Wv,
                         const float* __restrict__ Ws,
                         ushort* __restrict__ dhs, ushort* __restrict__ dWq,
                         ushort* __restrict__ dWk, ushort* __restrict__ dWv,
                         ushort* __restrict__ dWs)
{
    int bid = blockIdx.x;
    const float* src; ushort* dst; int off;
    if (bid < 2048)      { src = hs; dst = dhs; off = bid; }
    else if (bid < 2560) { src = Wq; dst = dWq; off = bid - 2048; }
    else if (bid < 3072) { src = Wk; dst = dWk; off = bid - 2560; }
    else if (bid < 3584) { src = Wv; dst = dWv; off = bid - 3072; }
    else                 { src = Ws; dst = dWs; off = bid - 3584; }
    int i = (off * 256 + threadIdx.x) * 8;
    float4 a = *(const float4*)(src + i);
    float4 b = *(const float4*)(src + i + 4);
    union { ushort u[8]; float4 v; } o;
    o.u[0] = f2bf(a.x); o.u[1] = f2bf(a.y); o.u[2] = f2bf(a.z); o.u[3] = f2bf(a.w);
    o.u[4] = f2bf(b.x); o.u[5] = f2bf(b.y); o.u[6] = f2bf(b.z); o.u[7] = f2bf(b.w);
    *(float4*)(dst + i) = o.v;
}

// Fused QKVS projection (structure unchanged). X:[4096,1024] bf16, W*:[N,1024] bf16, bias fp32.
// xb 0-7 -> Q (scaled 0.125*log2e), 8-15 -> K, 16-23 -> V (transposed to VtG[bh][d][s]),
// 24-25 -> S (sigmoid -> fp32 sb). LDS XOR chunk swizzle: chunk c of row r at slot c^(r&7).
__launch_bounds__(256, 4)
__global__ void fused_qkvs(const ushort* __restrict__ X,
                           const ushort* __restrict__ Wq, const ushort* __restrict__ Wk,
                           const ushort* __restrict__ Wv, const ushort* __restrict__ Ws,
                           const float* __restrict__ bq, const float* __restrict__ bk,
                           const float* __restrict__ bv, const float* __restrict__ bs,
                           ushort* __restrict__ Qb, ushort* __restrict__ Kb,
                           ushort* __restrict__ VtG, float* __restrict__ sb)
{
    __shared__ __align__(16) ushort Sm[128 * 136];
    ushort* As = Sm;
    ushort* Bs = Sm + 128 * 64;

    const int tid = threadIdx.x, w = tid >> 6, lane = tid & 63;
    const int l15 = lane & 15, quad = lane >> 4;
    const int lrow = lane >> 3;
    const int gchunk = ((lane & 7) ^ lrow) * 8;

    const int wid = blockIdx.x;
    const int r8 = wid & 7, jj = wid >> 3;
    const int by = (jj & 3) * 8 + r8;
    const int xb = jj >> 2;
    const int m0 = by * 128;

    const ushort* W; const float* bias; int n0, mode;
    if (xb < 8)       { W = Wq; bias = bq; n0 = xb * 128;        mode = 1; }
    else if (xb < 16) { W = Wk; bias = bk; n0 = (xb - 8) * 128;  mode = 0; }
    else if (xb < 24) { W = Wv; bias = bv; n0 = (xb - 16) * 128; mode = 2; }
    else              { W = Ws; bias = bs; n0 = (xb - 24) * 128; mode = 3; }

    const int wm = (w >> 1) * 64, wn = (w & 1) * 64;

    f32x4 acc[4][4];
    for (int i = 0; i < 4; i++) for (int j = 0; j < 4; j++) acc[i][j] = (f32x4){0.f, 0.f, 0.f, 0.f};

    for (int k0 = 0; k0 < 1024; k0 += 64) {
        __syncthreads();
        for (int c = 0; c < 4; ++c) {
            int r = w * 32 + c * 8;
            async_load16(&X[(size_t)(m0 + r + lrow) * 1024 + k0 + gchunk], &As[r * 64]);
            async_load16(&W[(size_t)(n0 + r + lrow) * 1024 + k0 + gchunk], &Bs[r * 64]);
        }
        __syncthreads();
        for (int kk = 0; kk < 64; kk += 32) {
            const int csw = quad + (kk >> 3);
            bf16x8 a[4], b[4];
            for (int i = 0; i < 4; i++)
                a[i] = *(const bf16x8*)&As[(wm + i * 16 + l15) * 64 + ((csw ^ (l15 & 7)) * 8)];
            for (int j = 0; j < 4; j++)
                b[j] = *(const bf16x8*)&Bs[(wn + j * 16 + l15) * 64 + ((csw ^ (l15 & 7)) * 8)];
            for (int i = 0; i < 4; i++)
                for (int j = 0; j < 4; j++)
                    acc[i][j] = __builtin_amdgcn_mfma_f32_16x16x32_bf16(a[i], b[j], acc[i][j], 0, 0, 0);
        }
    }

    const float QSCALE = 0.125f * 1.44269504f;

    if (mode == 3) {
        for (int i = 0; i < 4; i++)
            for (int j = 0; j < 4; j++) {
                int gn = n0 + wn + j * 16 + l15;
                float bv_ = bias[gn];
                for (int r = 0; r < 4; r++) {
                    int gm = m0 + wm + i * 16 + quad * 4 + r;
                    float v = acc[i][j][r] + bv_;
                    float sg = __builtin_amdgcn_rcpf(1.0f + __builtin_amdgcn_exp2f(-v * 1.44269504f));
                    sb[(size_t)gm * 256 + gn] = sg * 0.1f + 0.95f;
                }
            }
        return;
    }

    __syncthreads();

    if (mode == 2) {
        for (int i = 0; i < 4; i++)
            for (int j = 0; j < 4; j++) {
                int gnl = wn + j * 16 + l15;
                float bv_ = bias[n0 + gnl];
                ushort4 pk;
                pk.x = f2bf(acc[i][j][0] + bv_);
                pk.y = f2bf(acc[i][j][1] + bv_);
                pk.z = f2bf(acc[i][j][2] + bv_);
                pk.w = f2bf(acc[i][j][3] + bv_);
                *(ushort4*)&Sm[gnl * 136 + wm + i * 16 + quad * 4] = pk;
            }
        __syncthreads();
        const int bb = m0 >> 11, sloc = m0 & 2047;
        for (int it = 0; it < 8; ++it) {
            int d = (tid >> 4) + it * 16;
            int s8 = (tid & 15) * 8;
            float4 v = *(float4*)&Sm[d * 136 + s8];
            int h = (n0 + d) >> 6, dd = d & 63;
            *(float4*)&VtG[(size_t)(bb * 16 + h) * 131072 + (size_t)dd * 2048 + sloc + s8] = v;
        }
    } else {
        for (int i = 0; i < 4; i++)
            for (int j = 0; j < 4; j++) {
                int gnl = wn + j * 16 + l15;
                float bv_ = bias[n0 + gnl];
                for (int r = 0; r < 4; r++) {
                    float v = acc[i][j][r] + bv_;
                    if (mode == 1) v *= QSCALE;
                    Sm[(wm + i * 16 + quad * 4 + r) * 136 + gnl] = f2bf(v);
                }
            }
        __syncthreads();
        ushort* dst = (mode == 1) ? Qb : Kb;
        for (int it = 0; it < 8; ++it) {
            int row = (tid >> 4) + it * 16, c = (tid & 15) * 8;
            *(float4*)&dst[(size_t)(m0 + row) * 1024 + n0 + c] = *(float4*)&Sm[row * 136 + c];
        }
    }
}

// Flash attention v10: BQ=64, 128-thread blocks (2 waves, mt=2 each), grid 1024
// -> 4 blocks/CU (LDS 40KB), 4 independent barrier domains/CU.
// S^T formulation; raw v_exp_f32; precomputed loop-invariant LDS offsets.
// Q staged swizzled into the Ps region so tile-0 K/V prefetch overlaps Q staging.
__launch_bounds__(128, 2)
__global__ void attn_kernel(const ushort* __restrict__ Q, const ushort* __restrict__ K,
                            const ushort* __restrict__ Vt, const float* __restrict__ sb,
                            float* __restrict__ out)
{
    __shared__ __align__(16) ushort SmA[4 * 4096];   // 32KB: Ks0|Ks1|Vs0|Vs1
    __shared__ __align__(16) ushort Ps[4096];        // 8KB: 2 waves x 32rows x 64; Qs aliased
    ushort* Ks0 = SmA;
    ushort* Ks1 = SmA + 4096;
    ushort* Vs0 = SmA + 8192;
    ushort* Vs1 = SmA + 12288;
    ushort* Qs  = Ps;                                 // 64 rows x 64 (chunk-swizzled) = 8KB

    const int tid = threadIdx.x, w = tid >> 6, lane = tid & 63;
    const int l15 = lane & 15, quad = lane >> 4;
    const int lrow = lane >> 3;
    const int gchunk = ((lane & 7) ^ lrow) * 8;

    // XCD swizzle: same bh (same K/V) -> same XCD
    const int wid = blockIdx.x;
    const int r8 = wid & 7, jj = wid >> 3;
    const int bh = (jj & 3) * 8 + r8;    // 0..31
    const int qx = jj >> 2;              // 0..31
    const int b = bh >> 4, h = bh & 15;
    const int q0 = qx * 64;
    const size_t rowbase = (size_t)b * 2048;
    const int cbase = h * 64;

    // global staging bases (per-thread, loop-invariant)
    const ushort* kg = K + (rowbase + w * 32 + lrow) * 1024 + cbase + gchunk;
    const ushort* vg = Vt + (size_t)bh * 131072 + (size_t)(w * 32 + lrow) * 2048 + gchunk;

    // prefetch K/V tile 0 FIRST (distinct LDS region from Qs)
    for (int c = 0; c < 4; ++c) {
        async_load16(kg + c * 8192,  Ks0 + w * 2048 + c * 512);
        async_load16(vg + c * 16384, Vs0 + w * 2048 + c * 512);
    }

    // stage Q tile into Qs (pitch 64, XOR chunk swizzle), applying groupwise scale s
    for (int it = 0; it < 4; ++it) {
        int l = tid + it * 128;           // 0..511
        int r = l >> 3, ch = l & 7;       // row 0..63, global chunk 0..7
        int c = ch * 8;
        union { float4 f; ushort u[8]; } uu, oo;
        uu.f = *(const float4*)&Q[(rowbase + q0 + r) * 1024 + cbase + c];
        const float* sp = &sb[(rowbase + q0 + r) * 256 + ((cbase + c) >> 2)];
        float s0 = sp[0], s1 = sp[1];
        for (int j = 0; j < 4; j++) oo.u[j] = f2bf(bf2f(uu.u[j]) * s0);
        for (int j = 4; j < 8; j++) oo.u[j] = f2bf(bf2f(uu.u[j]) * s1);
        *(float4*)&Qs[r * 64 + ((ch ^ (r & 7)) * 8)] = oo.f;
    }
    __syncthreads();

    // hoist loop-invariant Q frags (MFMA B-operand: lane l15 = q-row)
    bf16x8 aq[2][2];  // [mt][kk2]
    for (int mt = 0; mt < 2; mt++)
        for (int kk2 = 0; kk2 < 2; kk2++)
            aq[mt][kk2] = *(const bf16x8*)&Qs[(w * 32 + mt * 16 + l15) * 64
                                              + (((kk2 * 4 + quad) ^ (l15 & 7)) * 8)];
    __syncthreads();   // all ds_reads of Qs drained; Ps region free

    // precomputed loop-invariant LDS offsets
    int kvoff[2][4];
    for (int kk2 = 0; kk2 < 2; kk2++)
        for (int nt = 0; nt < 4; nt++)
            kvoff[kk2][nt] = (nt * 16 + l15) * 64 + (((quad + kk2 * 4) ^ (l15 & 7)) * 8);
    int wroff[2][4], rdoff[2][2];
    {
        const int wrb = w * 2048 + l15 * 64 + (quad & 1) * 4;
        const int rdb = w * 2048 + l15 * 64;
        for (int mt = 0; mt < 2; mt++) {
            for (int kt2 = 0; kt2 < 4; kt2++)
                wroff[mt][kt2] = wrb + mt * 1024 + (((kt2 * 2 + (quad >> 1)) ^ (l15 & 7)) * 8);
            for (int half = 0; half < 2; half++)
                rdoff[mt][half] = rdb + mt * 1024 + (((half * 4 + quad) ^ (l15 & 7)) * 8);
        }
    }

    float lsum[2] = {0.f, 0.f};
    f32x4 o[2][4];
    for (int mt = 0; mt < 2; mt++) for (int nt = 0; nt < 4; nt++) o[mt][nt] = (f32x4){0.f, 0.f, 0.f, 0.f};
    const f32x4 z4 = (f32x4){0.f, 0.f, 0.f, 0.f};

#define ATTN_STEP(KC, VC, KN, VN, KT, PREFETCH)                                                         \
    {                                                                                                   \
        __syncthreads(); /* vmcnt drained: tile KT resident; buffers KN/VN free */                      \
        if (PREFETCH) {                                                                                 \
            const int nk = (KT) + 1;                                                                    \
            for (int c = 0; c < 4; ++c) {                                                               \
                async_load16(kg + nk * 65536 + c * 8192, KN + w * 2048 + c * 512);                      \
                async_load16(vg + nk * 64 + c * 16384,   VN + w * 2048 + c * 512);                      \
            }                                                                                           \
        }                                                                                               \
        bf16x8 kb[2][4], vb[2][4];                                                                      \
        for (int kk2 = 0; kk2 < 2; kk2++)                                                               \
            for (int nt = 0; nt < 4; nt++) {                                                            \
                kb[kk2][nt] = *(const bf16x8*)&KC[kvoff[kk2][nt]];                                      \
                vb[kk2][nt] = *(const bf16x8*)&VC[kvoff[kk2][nt]];                                      \
            }                                                                                           \
        /* S^T: A = K frag (m=key), B = Q frag (n=q-row) */                                             \
        f32x4 st[2][4];                                                                                 \
        for (int mt = 0; mt < 2; mt++)                                                                  \
            for (int kt2 = 0; kt2 < 4; kt2++) {                                                         \
                st[mt][kt2] = __builtin_amdgcn_mfma_f32_16x16x32_bf16(kb[0][kt2], aq[mt][0], z4, 0, 0, 0); \
                st[mt][kt2] = __builtin_amdgcn_mfma_f32_16x16x32_bf16(kb[1][kt2], aq[mt][1],            \
                                                                      st[mt][kt2], 0, 0, 0);            \
            }                                                                                           \
        for (int mt = 0; mt < 2; mt++)                                                                  \
            for (int kt2 = 0; kt2 < 4; kt2++) {                                                         \
                float p0 = __builtin_amdgcn_exp2f(st[mt][kt2][0]);                                      \
                float p1 = __builtin_amdgcn_exp2f(st[mt][kt2][1]);                                      \
                float p2 = __builtin_amdgcn_exp2f(st[mt][kt2][2]);                                      \
                float p3 = __builtin_amdgcn_exp2f(st[mt][kt2][3]);                                      \
                lsum[mt] += (p0 + p1) + (p2 + p3);                                                      \
                unsigned d0 = __builtin_amdgcn_perm(__builtin_bit_cast(unsigned, p1) + 0x8000u,         \
                                                    __builtin_bit_cast(unsigned, p0) + 0x8000u,         \
                                                    0x07060302u);                                       \
                unsigned d1 = __builtin_amdgcn_perm(__builtin_bit_cast(unsigned, p3) + 0x8000u,         \
                                                    __builtin_bit_cast(unsigned, p2) + 0x8000u,         \
                                                    0x07060302u);                                       \
                uint2 pk; pk.x = d0; pk.y = d1;                                                         \
                *(uint2*)&Ps[wroff[mt][kt2]] = pk;                                                      \
            }                                                                                           \
        /* O += P @ V (Ps strip wave-private; lgkmcnt ordering suffices) */                             \
        for (int half = 0; half < 2; half++) {                                                          \
            bf16x8 a_[2];                                                                               \
            for (int mt = 0; mt < 2; mt++)                                                              \
                a_[mt] = *(const bf16x8*)&Ps[rdoff[mt][half]];                                          \
            for (int mt = 0; mt < 2; mt++)                                                              \
                for (int nt = 0; nt < 4; nt++)                                                          \
                    o[mt][nt] = __builtin_amdgcn_mfma_f32_16x16x32_bf16(a_[mt], vb[half][nt],           \
                                                                        o[mt][nt], 0, 0, 0);            \
        }                                                                                               \
    }

    for (int kt = 0; kt < 32; kt += 2) {
        ATTN_STEP(Ks0, Vs0, Ks1, Vs1, kt, 1);
        ATTN_STEP(Ks1, Vs1, Ks0, Vs0, kt + 1, (kt + 2 < 32));
    }
#undef ATTN_STEP

    // finalize row sums: quads hold disjoint key subsets for q-row l15 -> xor-reduce
    float inv[2];
    for (int mt = 0; mt < 2; mt++) {
        float s = lsum[mt];
        s += __shfl_xor(s, 16);
        s += __shfl_xor(s, 32);
        inv[mt] = 1.0f / s;
    }

    for (int mt = 0; mt < 2; mt++) {
        for (int r = 0; r < 4; r++) {
            float iv = __shfl(inv[mt], quad * 4 + r);
            int q = q0 + w * 32 + mt * 16 + quad * 4 + r;
            size_t base = (rowbase + q) * 1024 + cbase;
            for (int nt = 0; nt < 4; nt++)
                out[base + nt * 16 + l15] = o[mt][nt][r] * iv;
        }
    }
}

extern "C" void kernel_launch(void* const* d_in, const int* in_sizes, int n_in,
                              void* d_out, int out_size, void* d_ws, size_t ws_size,
                              hipStream_t stream) {
    const float* hs = (const float*)d_in[0];
    const float* Wq = (const float*)d_in[1];
    const float* bq = (const float*)d_in[2];
    const float* Wk = (const float*)d_in[3];
    const float* bk = (const float*)d_in[4];
    const float* Wv = (const float*)d_in[5];
    const float* bv = (const float*)d_in[6];
    const float* Ws = (const float*)d_in[7];
    const float* bs = (const float*)d_in[8];
    float* outp = (float*)d_out;

    char* ws = (char*)d_ws;
    ushort* Qb    = (ushort*)(ws);                 //  8 MB
    ushort* Kb    = (ushort*)(ws + 8388608);       //  8 MB
    ushort* VtG   = (ushort*)(ws + 16777216);      //  8 MB (V transposed [bh][d][s])
    float*  sb    = (float* )(ws + 25165824);      //  4 MB
    ushort* hs_bf = (ushort*)(ws + 29360128);      //  8 MB
    ushort* Wq_bf = (ushort*)(ws + 37748736);      //  2 MB
    ushort* Wk_bf = (ushort*)(ws + 39845888);      //  2 MB
    ushort* Wv_bf = (ushort*)(ws + 41943040);      //  2 MB
    ushort* Ws_bf = (ushort*)(ws + 44040192);      // 0.5 MB -> total 44,564,480 B

    cast_all<<<dim3(3712), dim3(256), 0, stream>>>(hs, Wq, Wk, Wv, Ws,
                                                   hs_bf, Wq_bf, Wk_bf, Wv_bf, Ws_bf);
    fused_qkvs<<<dim3(832), dim3(256), 0, stream>>>(hs_bf, Wq_bf, Wk_bf, Wv_bf, Ws_bf,
                                                    bq, bk, bv, bs, Qb, Kb, VtG, sb);
    attn_kernel<<<dim3(1024), dim3(128), 0, stream>>>(Qb, Kb, VtG, sb, outp);
}

// Round 11
// 177.452 us; speedup vs baseline: 1.5893x; 1.0161x over previous
//
#include <hip/hip_runtime.h>

typedef short bf16x8 __attribute__((ext_vector_type(8)));
typedef float f32x4 __attribute__((ext_vector_type(4)));

__device__ inline float bf2f(ushort u) {
    unsigned v = ((unsigned)u) << 16;
    return __builtin_bit_cast(float, v);
}
__device__ inline ushort f2bf(float f) {
    unsigned u = __builtin_bit_cast(unsigned, f);
    u += 0x7fffu + ((u >> 16) & 1u);
    return (ushort)(u >> 16);
}
__device__ inline void async_load16(const ushort* g, ushort* l) {
    __builtin_amdgcn_global_load_lds((const __attribute__((address_space(1))) void*)g,
                                     (__attribute__((address_space(3))) void*)l, 16, 0, 0);
}

// Single merged fp32->bf16 cast for all 5 tensors. 8 elems/thread.
__global__ void cast_all(const float* __restrict__ hs, const float* __restrict__ Wq,
                         const float* __restrict__ Wk, const float* __restrict__ Wv,
                         const float* __restrict__ Ws,
                         ushort* __restrict__ dhs, ushort* __restrict__ dWq,
                         ushort* __restrict__ dWk, ushort* __restrict__ dWv,
                         ushort* __restrict__ dWs)
{
    int bid = blockIdx.x;
    const float* src; ushort* dst; int off;
    if (bid < 2048)      { src = hs; dst = dhs; off = bid; }
    else if (bid < 2560) { src = Wq; dst = dWq; off = bid - 2048; }
    else if (bid < 3072) { src = Wk; dst = dWk; off = bid - 2560; }
    else if (bid < 3584) { src = Wv; dst = dWv; off = bid - 3072; }
    else                 { src = Ws; dst = dWs; off = bid - 3584; }
    int i = (off * 256 + threadIdx.x) * 8;
    float4 a = *(const float4*)(src + i);
    float4 b = *(const float4*)(src + i + 4);
    union { ushort u[8]; float4 v; } o;
    o.u[0] = f2bf(a.x); o.u[1] = f2bf(a.y); o.u[2] = f2bf(a.z); o.u[3] = f2bf(a.w);
    o.u[4] = f2bf(b.x); o.u[5] = f2bf(b.y); o.u[6] = f2bf(b.z); o.u[7] = f2bf(b.w);
    *(float4*)(dst + i) = o.v;
}

// Fused QKVS projection (unchanged). X:[4096,1024] bf16, W*:[N,1024] bf16, bias fp32.
// xb 0-7 -> Q (scaled 0.125*log2e), 8-15 -> K, 16-23 -> V (transposed to VtG[bh][d][s]),
// 24-25 -> S (sigmoid -> fp32 sb). LDS XOR chunk swizzle: chunk c of row r at slot c^(r&7).
__launch_bounds__(256, 4)
__global__ void fused_qkvs(const ushort* __restrict__ X,
                           const ushort* __restrict__ Wq, const ushort* __restrict__ Wk,
                           const ushort* __restrict__ Wv, const ushort* __restrict__ Ws,
                           const float* __restrict__ bq, const float* __restrict__ bk,
                           const float* __restrict__ bv, const float* __restrict__ bs,
                           ushort* __restrict__ Qb, ushort* __restrict__ Kb,
                           ushort* __restrict__ VtG, float* __restrict__ sb)
{
    __shared__ __align__(16) ushort Sm[128 * 136];
    ushort* As = Sm;
    ushort* Bs = Sm + 128 * 64;

    const int tid = threadIdx.x, w = tid >> 6, lane = tid & 63;
    const int l15 = lane & 15, quad = lane >> 4;
    const int lrow = lane >> 3;
    const int gchunk = ((lane & 7) ^ lrow) * 8;

    const int wid = blockIdx.x;
    const int r8 = wid & 7, jj = wid >> 3;
    const int by = (jj & 3) * 8 + r8;
    const int xb = jj >> 2;
    const int m0 = by * 128;

    const ushort* W; const float* bias; int n0, mode;
    if (xb < 8)       { W = Wq; bias = bq; n0 = xb * 128;        mode = 1; }
    else if (xb < 16) { W = Wk; bias = bk; n0 = (xb - 8) * 128;  mode = 0; }
    else if (xb < 24) { W = Wv; bias = bv; n0 = (xb - 16) * 128; mode = 2; }
    else              { W = Ws; bias = bs; n0 = (xb - 24) * 128; mode = 3; }

    const int wm = (w >> 1) * 64, wn = (w & 1) * 64;

    f32x4 acc[4][4];
    for (int i = 0; i < 4; i++) for (int j = 0; j < 4; j++) acc[i][j] = (f32x4){0.f, 0.f, 0.f, 0.f};

    for (int k0 = 0; k0 < 1024; k0 += 64) {
        __syncthreads();
        for (int c = 0; c < 4; ++c) {
            int r = w * 32 + c * 8;
            async_load16(&X[(size_t)(m0 + r + lrow) * 1024 + k0 + gchunk], &As[r * 64]);
            async_load16(&W[(size_t)(n0 + r + lrow) * 1024 + k0 + gchunk], &Bs[r * 64]);
        }
        __syncthreads();
        for (int kk = 0; kk < 64; kk += 32) {
            const int csw = quad + (kk >> 3);
            bf16x8 a[4], b[4];
            for (int i = 0; i < 4; i++)
                a[i] = *(const bf16x8*)&As[(wm + i * 16 + l15) * 64 + ((csw ^ (l15 & 7)) * 8)];
            for (int j = 0; j < 4; j++)
                b[j] = *(const bf16x8*)&Bs[(wn + j * 16 + l15) * 64 + ((csw ^ (l15 & 7)) * 8)];
            for (int i = 0; i < 4; i++)
                for (int j = 0; j < 4; j++)
                    acc[i][j] = __builtin_amdgcn_mfma_f32_16x16x32_bf16(a[i], b[j], acc[i][j], 0, 0, 0);
        }
    }

    const float QSCALE = 0.125f * 1.44269504f;

    if (mode == 3) {
        for (int i = 0; i < 4; i++)
            for (int j = 0; j < 4; j++) {
                int gn = n0 + wn + j * 16 + l15;
                float bv_ = bias[gn];
                for (int r = 0; r < 4; r++) {
                    int gm = m0 + wm + i * 16 + quad * 4 + r;
                    float v = acc[i][j][r] + bv_;
                    float sg = __builtin_amdgcn_rcpf(1.0f + __builtin_amdgcn_exp2f(-v * 1.44269504f));
                    sb[(size_t)gm * 256 + gn] = sg * 0.1f + 0.95f;
                }
            }
        return;
    }

    __syncthreads();

    if (mode == 2) {
        for (int i = 0; i < 4; i++)
            for (int j = 0; j < 4; j++) {
                int gnl = wn + j * 16 + l15;
                float bv_ = bias[n0 + gnl];
                ushort4 pk;
                pk.x = f2bf(acc[i][j][0] + bv_);
                pk.y = f2bf(acc[i][j][1] + bv_);
                pk.z = f2bf(acc[i][j][2] + bv_);
                pk.w = f2bf(acc[i][j][3] + bv_);
                *(ushort4*)&Sm[gnl * 136 + wm + i * 16 + quad * 4] = pk;
            }
        __syncthreads();
        const int bb = m0 >> 11, sloc = m0 & 2047;
        for (int it = 0; it < 8; ++it) {
            int d = (tid >> 4) + it * 16;
            int s8 = (tid & 15) * 8;
            float4 v = *(float4*)&Sm[d * 136 + s8];
            int h = (n0 + d) >> 6, dd = d & 63;
            *(float4*)&VtG[(size_t)(bb * 16 + h) * 131072 + (size_t)dd * 2048 + sloc + s8] = v;
        }
    } else {
        for (int i = 0; i < 4; i++)
            for (int j = 0; j < 4; j++) {
                int gnl = wn + j * 16 + l15;
                float bv_ = bias[n0 + gnl];
                for (int r = 0; r < 4; r++) {
                    float v = acc[i][j][r] + bv_;
                    if (mode == 1) v *= QSCALE;
                    Sm[(wm + i * 16 + quad * 4 + r) * 136 + gnl] = f2bf(v);
                }
            }
        __syncthreads();
        ushort* dst = (mode == 1) ? Qb : Kb;
        for (int it = 0; it < 8; ++it) {
            int row = (tid >> 4) + it * 16, c = (tid & 15) * 8;
            *(float4*)&dst[(size_t)(m0 + row) * 1024 + n0 + c] = *(float4*)&Sm[row * 136 + c];
        }
    }
}

// Flash attention v11: LDS 36KB -> 4 blocks/CU. Ps is a 4KB per-wave 16-row strip,
// processed per-mt (mt1's QK overlaps mt0's PV); Qs aliases Ks1's region (dead until
// STEP(0) prefetch). BQ=64, 128-thread blocks, grid 1024, S^T formulation, raw v_exp.
__launch_bounds__(128, 2)
__global__ void attn_kernel(const ushort* __restrict__ Q, const ushort* __restrict__ K,
                            const ushort* __restrict__ Vt, const float* __restrict__ sb,
                            float* __restrict__ out)
{
    __shared__ __align__(16) ushort SmA[4 * 4096];   // 32KB: Ks0|Ks1|Vs0|Vs1
    __shared__ __align__(16) ushort Ps[2048];        // 4KB: 2 waves x (16 rows x 64)
    ushort* Ks0 = SmA;
    ushort* Ks1 = SmA + 4096;
    ushort* Vs0 = SmA + 8192;
    ushort* Vs1 = SmA + 12288;
    ushort* Qs  = SmA + 4096;    // aliases Ks1: dead until STEP(0)'s prefetch (post-hoist)

    const int tid = threadIdx.x, w = tid >> 6, lane = tid & 63;
    const int l15 = lane & 15, quad = lane >> 4;
    const int lrow = lane >> 3;
    const int gchunk = ((lane & 7) ^ lrow) * 8;

    // XCD swizzle: same bh (same K/V) -> same XCD
    const int wid = blockIdx.x;
    const int r8 = wid & 7, jj = wid >> 3;
    const int bh = (jj & 3) * 8 + r8;    // 0..31
    const int qx = jj >> 2;              // 0..31
    const int b = bh >> 4, h = bh & 15;
    const int q0 = qx * 64;
    const size_t rowbase = (size_t)b * 2048;
    const int cbase = h * 64;

    // global staging bases (per-thread, loop-invariant)
    const ushort* kg = K + (rowbase + w * 32 + lrow) * 1024 + cbase + gchunk;
    const ushort* vg = Vt + (size_t)bh * 131072 + (size_t)(w * 32 + lrow) * 2048 + gchunk;

    // prefetch K/V tile 0 FIRST (Ks0/Vs0 disjoint from Qs alias)
    for (int c = 0; c < 4; ++c) {
        async_load16(kg + c * 8192,  Ks0 + w * 2048 + c * 512);
        async_load16(vg + c * 16384, Vs0 + w * 2048 + c * 512);
    }

    // stage Q tile into Qs (pitch 64, XOR chunk swizzle), applying groupwise scale s
    for (int it = 0; it < 4; ++it) {
        int l = tid + it * 128;           // 0..511
        int r = l >> 3, ch = l & 7;       // row 0..63, chunk 0..7
        int c = ch * 8;
        union { float4 f; ushort u[8]; } uu, oo;
        uu.f = *(const float4*)&Q[(rowbase + q0 + r) * 1024 + cbase + c];
        const float* sp = &sb[(rowbase + q0 + r) * 256 + ((cbase + c) >> 2)];
        float s0 = sp[0], s1 = sp[1];
        for (int j = 0; j < 4; j++) oo.u[j] = f2bf(bf2f(uu.u[j]) * s0);
        for (int j = 4; j < 8; j++) oo.u[j] = f2bf(bf2f(uu.u[j]) * s1);
        *(float4*)&Qs[r * 64 + ((ch ^ (r & 7)) * 8)] = oo.f;
    }
    __syncthreads();   // Qs writes visible to all waves

    // hoist loop-invariant Q frags (MFMA B-operand: lane l15 = q-row)
    bf16x8 aq[2][2];  // [mt][kk2]
    for (int mt = 0; mt < 2; mt++)
        for (int kk2 = 0; kk2 < 2; kk2++)
            aq[mt][kk2] = *(const bf16x8*)&Qs[(w * 32 + mt * 16 + l15) * 64
                                              + (((kk2 * 4 + quad) ^ (l15 & 7)) * 8)];
    // (STEP(0)'s barrier drains these ds_reads before Ks1 gets overwritten)

    // precomputed loop-invariant LDS offsets
    int kvoff[2][4];
    for (int kk2 = 0; kk2 < 2; kk2++)
        for (int nt = 0; nt < 4; nt++)
            kvoff[kk2][nt] = (nt * 16 + l15) * 64 + (((quad + kk2 * 4) ^ (l15 & 7)) * 8);
    int wroff2[4], rdoff2[2];
    {
        const int base = w * 1024 + l15 * 64;
        for (int kt2 = 0; kt2 < 4; kt2++)
            wroff2[kt2] = base + (quad & 1) * 4 + (((kt2 * 2 + (quad >> 1)) ^ (l15 & 7)) * 8);
        for (int half = 0; half < 2; half++)
            rdoff2[half] = base + (((half * 4 + quad) ^ (l15 & 7)) * 8);
    }

    float lsum[2] = {0.f, 0.f};
    f32x4 o[2][4];
    for (int mt = 0; mt < 2; mt++) for (int nt = 0; nt < 4; nt++) o[mt][nt] = (f32x4){0.f, 0.f, 0.f, 0.f};
    const f32x4 z4 = (f32x4){0.f, 0.f, 0.f, 0.f};

#define ATTN_STEP(KC, VC, KN, VN, KT, PREFETCH)                                                         \
    {                                                                                                   \
        __syncthreads(); /* vmcnt+lgkm drained: tile KT resident; buffers KN/VN free */                 \
        if (PREFETCH) {                                                                                 \
            const int nk = (KT) + 1;                                                                    \
            for (int c = 0; c < 4; ++c) {                                                               \
                async_load16(kg + nk * 65536 + c * 8192, KN + w * 2048 + c * 512);                      \
                async_load16(vg + nk * 64 + c * 16384,   VN + w * 2048 + c * 512);                      \
            }                                                                                           \
        }                                                                                               \
        bf16x8 kb[2][4], vb[2][4];                                                                      \
        for (int kk2 = 0; kk2 < 2; kk2++)                                                               \
            for (int nt = 0; nt < 4; nt++) {                                                            \
                kb[kk2][nt] = *(const bf16x8*)&KC[kvoff[kk2][nt]];                                      \
                vb[kk2][nt] = *(const bf16x8*)&VC[kvoff[kk2][nt]];                                      \
            }                                                                                           \
        for (int mt = 0; mt < 2; mt++) {                                                                \
            /* S^T: A = K frag (m=key), B = Q frag (n=q-row) */                                         \
            f32x4 st[4];                                                                                \
            for (int kt2 = 0; kt2 < 4; kt2++) {                                                         \
                st[kt2] = __builtin_amdgcn_mfma_f32_16x16x32_bf16(kb[0][kt2], aq[mt][0], z4, 0, 0, 0);  \
                st[kt2] = __builtin_amdgcn_mfma_f32_16x16x32_bf16(kb[1][kt2], aq[mt][1], st[kt2],       \
                                                                  0, 0, 0);                             \
            }                                                                                           \
            for (int kt2 = 0; kt2 < 4; kt2++) {                                                         \
                float p0 = __builtin_amdgcn_exp2f(st[kt2][0]);                                          \
                float p1 = __builtin_amdgcn_exp2f(st[kt2][1]);                                          \
                float p2 = __builtin_amdgcn_exp2f(st[kt2][2]);                                          \
                float p3 = __builtin_amdgcn_exp2f(st[kt2][3]);                                          \
                lsum[mt] += (p0 + p1) + (p2 + p3);                                                      \
                unsigned d0 = __builtin_amdgcn_perm(__builtin_bit_cast(unsigned, p1) + 0x8000u,         \
                                                    __builtin_bit_cast(unsigned, p0) + 0x8000u,         \
                                                    0x07060302u);                                       \
                unsigned d1 = __builtin_amdgcn_perm(__builtin_bit_cast(unsigned, p3) + 0x8000u,         \
                                                    __builtin_bit_cast(unsigned, p2) + 0x8000u,         \
                                                    0x07060302u);                                       \
                uint2 pk; pk.x = d0; pk.y = d1;                                                         \
                *(uint2*)&Ps[wroff2[kt2]] = pk;                                                         \
            }                                                                                           \
            /* O += P @ V (strip wave-private; in-wave DS ordering covers WAR on mt=1) */               \
            for (int half = 0; half < 2; half++) {                                                      \
                bf16x8 a_ = *(const bf16x8*)&Ps[rdoff2[half]];                                          \
                for (int nt = 0; nt < 4; nt++)                                                          \
                    o[mt][nt] = __builtin_amdgcn_mfma_f32_16x16x32_bf16(a_, vb[half][nt],               \
                                                                        o[mt][nt], 0, 0, 0);            \
            }                                                                                           \
        }                                                                                               \
    }

    for (int kt = 0; kt < 32; kt += 2) {
        ATTN_STEP(Ks0, Vs0, Ks1, Vs1, kt, 1);
        ATTN_STEP(Ks1, Vs1, Ks0, Vs0, kt + 1, (kt + 2 < 32));
    }
#undef ATTN_STEP

    // finalize row sums: quads hold disjoint key subsets for q-row l15 -> xor-reduce
    float inv[2];
    for (int mt = 0; mt < 2; mt++) {
        float s = lsum[mt];
        s += __shfl_xor(s, 16);
        s += __shfl_xor(s, 32);
        inv[mt] = __builtin_amdgcn_rcpf(s);
    }

    for (int mt = 0; mt < 2; mt++) {
        for (int r = 0; r < 4; r++) {
            float iv = __shfl(inv[mt], quad * 4 + r);
            int q = q0 + w * 32 + mt * 16 + quad * 4 + r;
            size_t base = (rowbase + q) * 1024 + cbase;
            for (int nt = 0; nt < 4; nt++)
                out[base + nt * 16 + l15] = o[mt][nt][r] * iv;
        }
    }
}

extern "C" void kernel_launch(void* const* d_in, const int* in_sizes, int n_in,
                              void* d_out, int out_size, void* d_ws, size_t ws_size,
                              hipStream_t stream) {
    const float* hs = (const float*)d_in[0];
    const float* Wq = (const float*)d_in[1];
    const float* bq = (const float*)d_in[2];
    const float* Wk = (const float*)d_in[3];
    const float* bk = (const float*)d_in[4];
    const float* Wv = (const float*)d_in[5];
    const float* bv = (const float*)d_in[6];
    const float* Ws = (const float*)d_in[7];
    const float* bs = (const float*)d_in[8];
    float* outp = (float*)d_out;

    char* ws = (char*)d_ws;
    ushort* Qb    = (ushort*)(ws);                 //  8 MB
    ushort* Kb    = (ushort*)(ws + 8388608);       //  8 MB
    ushort* VtG   = (ushort*)(ws + 16777216);      //  8 MB (V transposed [bh][d][s])
    float*  sb    = (float* )(ws + 25165824);      //  4 MB
    ushort* hs_bf = (ushort*)(ws + 29360128);      //  8 MB
    ushort* Wq_bf = (ushort*)(ws + 37748736);      //  2 MB
    ushort* Wk_bf = (ushort*)(ws + 39845888);      //  2 MB
    ushort* Wv_bf = (ushort*)(ws + 41943040);      //  2 MB
    ushort* Ws_bf = (ushort*)(ws + 44040192);      // 0.5 MB -> total 44,564,480 B

    cast_all<<<dim3(3712), dim3(256), 0, stream>>>(hs, Wq, Wk, Wv, Ws,
                                                   hs_bf, Wq_bf, Wk_bf, Wv_bf, Ws_bf);
    fused_qkvs<<<dim3(832), dim3(256), 0, stream>>>(hs_bf, Wq_bf, Wk_bf, Wv_bf, Ws_bf,
                                                    bq, bk, bv, bs, Qb, Kb, VtG, sb);
    attn_kernel<<<dim3(1024), dim3(128), 0, stream>>>(Qb, Kb, VtG, sb, outp);
}